// Round 1
// baseline (3700.509 us; speedup 1.0000x reference)
//
#include <hip/hip_runtime.h>
#include <math.h>

#define DD    128
#define TWOD  256
#define FOURD 512
#define G4    2048
#define NBN   30
#define BQ    4096
#define FEWN  5
#define KTOT  768   // 256 (query) + 512 (h_r)

__device__ __forceinline__ float sigmoidf_(float x) { return 1.0f / (1.0f + expf(-x)); }

// ---------------- K0: one-time weight transposes into workspace ----------------
__global__ __launch_bounds__(256) void k_transpose(
    const float* __restrict__ Wih, const float* __restrict__ Whh,
    const float* __restrict__ p1W, const float* __restrict__ p2W,
    const float* __restrict__ nW, const float* __restrict__ nvW,
    float* __restrict__ WcatT, float* __restrict__ p1WT, float* __restrict__ p2WT,
    float* __restrict__ nWT, float* __restrict__ nvWT)
{
    int idx = blockIdx.x * 256 + threadIdx.x;
    int stride = gridDim.x * 256;
    // WcatT[j][g] = j<256 ? Wih[g][j] : Whh[g][j-256]   (reads coalesced along j)
    for (int i = idx; i < G4 * KTOT; i += stride) {
        int g = i / KTOT, j = i % KTOT;
        float v = (j < TWOD) ? Wih[g * TWOD + j] : Whh[g * FOURD + (j - TWOD)];
        WcatT[(size_t)j * G4 + g] = v;
    }
    for (int i = idx; i < FOURD * TWOD; i += stride) {
        int o = i / TWOD, j = i % TWOD;
        p1WT[j * FOURD + o] = p1W[o * TWOD + j];
    }
    for (int i = idx; i < TWOD * FOURD; i += stride) {
        int o = i / FOURD, j = i % FOURD;
        p2WT[j * TWOD + o] = p2W[o * FOURD + j];
    }
    for (int i = idx; i < DD * TWOD; i += stride) {
        int o = i / TWOD, j = i % TWOD;
        nWT[j * DD + o]  = nW[o * TWOD + j];
        nvWT[j * DD + o] = nvW[o * TWOD + j];
    }
}

// ---------------- K1: neighbor encoder (gather + attention + pool + tanh) ------
// grid: (2*BQ + 2*FEW, 2 paths), block 256
__global__ __launch_bounds__(256) void k_neighbor(
    const float* __restrict__ emb, const float* __restrict__ emb_var,
    const float* __restrict__ nWT, const float* __restrict__ nWb,
    const float* __restrict__ nu, const float* __restrict__ nub,
    const float* __restrict__ nvWT, const float* __restrict__ nvWb,
    const float* __restrict__ nvu, const float* __restrict__ nvub,
    const int* __restrict__ q_left, const int* __restrict__ q_right,
    const int* __restrict__ s_left, const int* __restrict__ s_right,
    float* __restrict__ query, float* __restrict__ support)
{
    const int row = blockIdx.x;
    const int p   = blockIdx.y;
    const int tid = threadIdx.x;

    const int* conn; float* dst;
    if (row < BQ)                { conn = q_left  + row * (NBN * 2);              dst = query   + ((size_t)p * BQ  + row) * TWOD; }
    else if (row < 2 * BQ)       { conn = q_right + (row - BQ) * (NBN * 2);       dst = query   + ((size_t)p * BQ  + (row - BQ)) * TWOD + DD; }
    else if (row < 2 * BQ + FEWN){ conn = s_left  + (row - 2 * BQ) * (NBN * 2);   dst = support + ((size_t)p * FEWN + (row - 2 * BQ)) * TWOD; }
    else                         { conn = s_right + (row - 2 * BQ - FEWN) * (NBN * 2);
                                   dst = support + ((size_t)p * FEWN + (row - 2 * BQ - FEWN)) * TWOD + DD; }

    const float* tbl = p ? emb_var : emb;
    const float* WT  = p ? nvWT : nWT;
    const float* Wb  = p ? nvWb : nWb;
    const float* uu  = p ? nvu  : nu;
    const float  ubb = p ? nvub[0] : nub[0];

    __shared__ int   sidx[NBN * 2];
    __shared__ float cat[32][260];        // rows 30,31 zero-padded; +4 col pad
    __shared__ float entE[NBN][DD];       // emb[ent] rows (pooled in BOTH paths)
    __shared__ float scoresP[4][32];
    __shared__ float scores[32];
    __shared__ float att[NBN];

    if (tid < NBN * 2) sidx[tid] = conn[tid];
    __syncthreads();

    for (int k = 0; k < 32; ++k) {
        int j = tid;
        float v = 0.f;
        if (k < NBN) {
            int r = (j < DD) ? sidx[2 * k] : sidx[2 * k + 1];
            v = tbl[(size_t)r * DD + (j & (DD - 1))];
        }
        cat[k][j] = v;
    }
    for (int it = 0; it < 15; ++it) {           // 30*128/256
        int idx = it * 256 + tid;
        int k = idx >> 7, j = idx & 127;
        entE[k][j] = emb[(size_t)sidx[2 * k + 1] * DD + j];
    }
    __syncthreads();

    // a[k] = u . tanh(W cat_k + b) + ub ; thread tile: 4 hidden-i x 4 neighbors-k
    const int iq = tid >> 3;     // 0..31  -> i = iq*4..+4
    const int kg = tid & 7;      // 0..7   -> k = kg*4..+4
    const int k0 = kg * 4;
    float acc[4][4] = {};        // acc[ii][kk]

    for (int j = 0; j < TWOD; j += 4) {
        float w[4][4] __attribute__((aligned(16)));   // w[jj][ii]
        *(float4*)w[0] = *(const float4*)(WT + (j + 0) * DD + iq * 4);
        *(float4*)w[1] = *(const float4*)(WT + (j + 1) * DD + iq * 4);
        *(float4*)w[2] = *(const float4*)(WT + (j + 2) * DD + iq * 4);
        *(float4*)w[3] = *(const float4*)(WT + (j + 3) * DD + iq * 4);
        float c[4][4] __attribute__((aligned(16)));   // c[kk][jj]
        *(float4*)c[0] = *(const float4*)&cat[k0 + 0][j];
        *(float4*)c[1] = *(const float4*)&cat[k0 + 1][j];
        *(float4*)c[2] = *(const float4*)&cat[k0 + 2][j];
        *(float4*)c[3] = *(const float4*)&cat[k0 + 3][j];
#pragma unroll
        for (int kk = 0; kk < 4; ++kk)
#pragma unroll
            for (int jj = 0; jj < 4; ++jj)
#pragma unroll
                for (int ii = 0; ii < 4; ++ii)
                    acc[ii][kk] += w[jj][ii] * c[kk][jj];
    }

    float pa[4] = {0.f, 0.f, 0.f, 0.f};
#pragma unroll
    for (int ii = 0; ii < 4; ++ii) {
        int i = iq * 4 + ii;
        float wbi = Wb[i], ui = uu[i];
#pragma unroll
        for (int kk = 0; kk < 4; ++kk)
            pa[kk] += ui * tanhf(acc[ii][kk] + wbi);
    }
#pragma unroll
    for (int off = 8; off < 64; off <<= 1)
#pragma unroll
        for (int kk = 0; kk < 4; ++kk)
            pa[kk] += __shfl_xor(pa[kk], off, 64);
    const int wv = tid >> 6, lane = tid & 63;
    if (lane < 8) {
#pragma unroll
        for (int kk = 0; kk < 4; ++kk) scoresP[wv][lane * 4 + kk] = pa[kk];
    }
    __syncthreads();
    if (tid < 32)
        scores[tid] = ubb + scoresP[0][tid] + scoresP[1][tid] + scoresP[2][tid] + scoresP[3][tid];
    __syncthreads();
    if (tid == 0) {
        float mx = -1e30f;
        for (int k = 0; k < NBN; ++k) mx = fmaxf(mx, scores[k]);
        float sum = 0.f;
        for (int k = 0; k < NBN; ++k) { float e = expf(scores[k] - mx); att[k] = e; sum += e; }
        float inv = 1.f / sum;
        for (int k = 0; k < NBN; ++k) att[k] *= inv;
    }
    __syncthreads();
    if (tid < DD) {
        float pooled = 0.f;
        for (int k = 0; k < NBN; ++k) pooled += att[k] * entE[k][tid];
        dst[tid] = tanhf(pooled);
    }
}

// ---------------- K2: support encoder (MLP + residual + layernorm ddof=1) ------
template <int RPB>
__global__ __launch_bounds__(256) void k_supenc(
    const float* __restrict__ xin, float* __restrict__ xout,
    const float* __restrict__ p1WT, const float* __restrict__ p1b,
    const float* __restrict__ p2WT, const float* __restrict__ p2b,
    const float* __restrict__ ln_a, const float* __restrict__ ln_b)
{
    const int tid = threadIdx.x;
    const int r0 = blockIdx.x * RPB;
    __shared__ float X[RPB][TWOD];
    __shared__ float H1[RPB][FOURD];
    __shared__ float red[4][RPB][2];
    __shared__ float muv[RPB], sgv[RPB];

    for (int idx = tid; idx < RPB * TWOD; idx += 256) {
        int r = idx >> 8, j = idx & 255;
        X[r][j] = xin[(size_t)(r0 + r) * TWOD + j];
    }
    __syncthreads();

    {   // h1 = relu(X p1W^T + b1); thread owns o = tid, tid+256
        float acc[RPB][2] = {};
        for (int j = 0; j < TWOD; j += 4) {
            float w0[4], w1[4];
#pragma unroll
            for (int jj = 0; jj < 4; ++jj) {
                w0[jj] = p1WT[(j + jj) * FOURD + tid];
                w1[jj] = p1WT[(j + jj) * FOURD + tid + 256];
            }
#pragma unroll
            for (int r = 0; r < RPB; ++r) {
                float x[4] __attribute__((aligned(16)));
                *(float4*)x = *(const float4*)&X[r][j];
#pragma unroll
                for (int jj = 0; jj < 4; ++jj) {
                    acc[r][0] += x[jj] * w0[jj];
                    acc[r][1] += x[jj] * w1[jj];
                }
            }
        }
        float b0 = p1b[tid], b1 = p1b[tid + 256];
#pragma unroll
        for (int r = 0; r < RPB; ++r) {
            H1[r][tid]       = fmaxf(acc[r][0] + b0, 0.f);
            H1[r][tid + 256] = fmaxf(acc[r][1] + b1, 0.f);
        }
    }
    __syncthreads();

    float z[RPB];
    {   // h2 = H1 p2W^T + b2; z = h2 + x
        float acc[RPB] = {};
        for (int j = 0; j < FOURD; j += 4) {
            float w[4];
#pragma unroll
            for (int jj = 0; jj < 4; ++jj) w[jj] = p2WT[(j + jj) * TWOD + tid];
#pragma unroll
            for (int r = 0; r < RPB; ++r) {
                float h[4] __attribute__((aligned(16)));
                *(float4*)h = *(const float4*)&H1[r][j];
#pragma unroll
                for (int jj = 0; jj < 4; ++jj) acc[r] += h[jj] * w[jj];
            }
        }
        float b = p2b[tid];
#pragma unroll
        for (int r = 0; r < RPB; ++r) z[r] = acc[r] + b + X[r][tid];
    }
    {   // layernorm, Bessel (ddof=1), eps added to sigma (not var)
        float s[RPB], ss[RPB];
#pragma unroll
        for (int r = 0; r < RPB; ++r) { s[r] = z[r]; ss[r] = z[r] * z[r]; }
#pragma unroll
        for (int off = 1; off < 64; off <<= 1)
#pragma unroll
            for (int r = 0; r < RPB; ++r) {
                s[r]  += __shfl_xor(s[r],  off, 64);
                ss[r] += __shfl_xor(ss[r], off, 64);
            }
        const int wv = tid >> 6, lane = tid & 63;
        if (lane == 0) {
#pragma unroll
            for (int r = 0; r < RPB; ++r) { red[wv][r][0] = s[r]; red[wv][r][1] = ss[r]; }
        }
        __syncthreads();
        if (tid < RPB) {
            float st  = red[0][tid][0] + red[1][tid][0] + red[2][tid][0] + red[3][tid][0];
            float sst = red[0][tid][1] + red[1][tid][1] + red[2][tid][1] + red[3][tid][1];
            float mu  = st / (float)TWOD;
            float var = fmaxf((sst - (float)TWOD * mu * mu) / ((float)TWOD - 1.f), 0.f);
            muv[tid] = mu; sgv[tid] = sqrtf(var);
        }
        __syncthreads();
    }
#pragma unroll
    for (int r = 0; r < RPB; ++r) {
        float o = (z[r] - muv[r]) / (sgv[r] + 1e-3f) * ln_a[tid] + ln_b[tid];
        xout[(size_t)(r0 + r) * TWOD + tid] = o;
    }
}

// ---------------- K4a: LSTM gates GEMM + cell update ---------------------------
// grid (BQ/32, 2), block 512 (8 waves; wave owns 4 rows)
__global__ __launch_bounds__(512) void k_lstm_gates(
    const float* __restrict__ qg, const float* __restrict__ hr,
    float* __restrict__ cst, float* __restrict__ h512,
    const float* __restrict__ WcatT,
    const float* __restrict__ bih, const float* __restrict__ bhh)
{
    const int tid = threadIdx.x;
    const int p   = blockIdx.y;
    const int r0  = blockIdx.x * 32;
    const int rq  = tid >> 6;       // wave id 0..7 -> rows rq*4..+4
    const int lu  = tid & 63;
    __shared__ float Xt[32][TWOD];

    for (int cc = 0; cc < 8; ++cc) {
        const int u = cc * 64 + lu;             // hidden unit 0..511
        float acc[4][4];                        // [row][gate i,f,g,o]
        {
            float b0 = bih[u]        + bhh[u];
            float b1 = bih[u + 512]  + bhh[u + 512];
            float b2 = bih[u + 1024] + bhh[u + 1024];
            float b3 = bih[u + 1536] + bhh[u + 1536];
#pragma unroll
            for (int r = 0; r < 4; ++r) { acc[r][0] = b0; acc[r][1] = b1; acc[r][2] = b2; acc[r][3] = b3; }
        }
        for (int kt = 0; kt < 3; ++kt) {
            __syncthreads();
            for (int it = 0; it < 4; ++it) {    // stage X tile [32][256]
                int flat = (it * 512 + tid) * 4;
                int r = flat >> 8, j = flat & 255;
                int row = r0 + r;
                const float* src;
                if (kt == 0) src = qg + ((size_t)p * BQ + row) * TWOD + j;
                else         src = hr + ((size_t)p * BQ + row) * FOURD + (kt - 1) * TWOD + j;
                *(float4*)&Xt[r][j] = *(const float4*)src;
            }
            __syncthreads();
            const float* Wbase = WcatT + (size_t)kt * TWOD * G4;
            for (int j = 0; j < TWOD; j += 4) {
                float w[4][4];                  // w[jj][gate]
#pragma unroll
                for (int jj = 0; jj < 4; ++jj) {
                    const float* wr = Wbase + (size_t)(j + jj) * G4 + u;
                    w[jj][0] = wr[0]; w[jj][1] = wr[512]; w[jj][2] = wr[1024]; w[jj][3] = wr[1536];
                }
#pragma unroll
                for (int r = 0; r < 4; ++r) {
                    float x[4] __attribute__((aligned(16)));
                    *(float4*)x = *(const float4*)&Xt[rq * 4 + r][j];
#pragma unroll
                    for (int jj = 0; jj < 4; ++jj)
#pragma unroll
                        for (int gg = 0; gg < 4; ++gg)
                            acc[r][gg] += x[jj] * w[jj][gg];
                }
            }
        }
#pragma unroll
        for (int r = 0; r < 4; ++r) {
            int row = r0 + rq * 4 + r;
            size_t cidx = ((size_t)p * BQ + row) * FOURD + u;
            float ig = sigmoidf_(acc[r][0]);
            float fg = sigmoidf_(acc[r][1]);
            float gv = tanhf(acc[r][2]);
            float og = sigmoidf_(acc[r][3]);
            float cn = fg * cst[cidx] + ig * gv;
            cst[cidx]  = cn;
            h512[cidx] = og * tanhf(cn);
        }
    }
}

// ---------------- K4b: h, attention over support, h_r update -------------------
// grid (BQ/32, 2), block 256 (4 waves; wave owns 8 rows)
__global__ __launch_bounds__(256) void k_lstm_attn(
    const float* __restrict__ qg, const float* __restrict__ h512,
    const float* __restrict__ sg, float* __restrict__ hr, float* __restrict__ hfin)
{
    const int tid = threadIdx.x;
    const int p   = blockIdx.y;
    const int wv = tid >> 6, lane = tid & 63;
    __shared__ float sgl[FEWN][TWOD];
    for (int idx = tid; idx < FEWN * TWOD; idx += 256)
        sgl[idx >> 8][idx & 255] = sg[p * FEWN * TWOD + idx];
    __syncthreads();
    const int j0 = lane * 4;
    for (int rr = 0; rr < 8; ++rr) {
        int row = blockIdx.x * 32 + wv * 8 + rr;
        size_t base = ((size_t)p * BQ + row) * TWOD + j0;
        float4 q4 = *(const float4*)(qg + base);
        float4 t4 = *(const float4*)(h512 + ((size_t)p * BQ + row) * FOURD + j0);
        float h[4] __attribute__((aligned(16))) = {q4.x + t4.x, q4.y + t4.y, q4.z + t4.z, q4.w + t4.w};
        float sv[FEWN][4] __attribute__((aligned(16)));
        float pa[FEWN];
#pragma unroll
        for (int f = 0; f < FEWN; ++f) {
            *(float4*)sv[f] = *(const float4*)&sgl[f][j0];
            pa[f] = h[0] * sv[f][0] + h[1] * sv[f][1] + h[2] * sv[f][2] + h[3] * sv[f][3];
        }
#pragma unroll
        for (int off = 1; off < 64; off <<= 1)
#pragma unroll
            for (int f = 0; f < FEWN; ++f) pa[f] += __shfl_xor(pa[f], off, 64);
        float mx = pa[0];
#pragma unroll
        for (int f = 1; f < FEWN; ++f) mx = fmaxf(mx, pa[f]);
        float sum = 0.f, e[FEWN];
#pragma unroll
        for (int f = 0; f < FEWN; ++f) { e[f] = expf(pa[f] - mx); sum += e[f]; }
        float inv = 1.f / sum;
        float r4[4] __attribute__((aligned(16))) = {0.f, 0.f, 0.f, 0.f};
#pragma unroll
        for (int f = 0; f < FEWN; ++f) {
            float a = e[f] * inv;
#pragma unroll
            for (int q = 0; q < 4; ++q) r4[q] += a * sv[f][q];
        }
        size_t hrbase = ((size_t)p * BQ + row) * FOURD;
        *(float4*)(hr + hrbase + j0)        = *(float4*)h;
        *(float4*)(hr + hrbase + TWOD + j0) = *(float4*)r4;
        *(float4*)(hfin + base)             = *(float4*)h;
    }
}

// ---------------- K5: final scores ---------------------------------------------
__global__ __launch_bounds__(256) void k_score(
    const float* __restrict__ hfin, const float* __restrict__ sg, float* __restrict__ out)
{
    const int tid = threadIdx.x;
    const int p   = blockIdx.y;
    __shared__ float sm[TWOD];
    if (tid < TWOD) {
        const float* s = sg + p * FEWN * TWOD + tid;
        sm[tid] = (s[0] + s[TWOD] + s[2 * TWOD] + s[3 * TWOD] + s[4 * TWOD]) / 5.0f;
    }
    __syncthreads();
    const int wv = tid >> 6, lane = tid & 63;
    const int j0 = lane * 4;
    for (int rr = 0; rr < 8; ++rr) {
        int row = blockIdx.x * 32 + wv * 8 + rr;
        const float* h = hfin + ((size_t)p * BQ + row) * TWOD + j0;
        float4 h4 = *(const float4*)h;
        float4 s4 = *(const float4*)&sm[j0];
        float pv = h4.x * s4.x + h4.y * s4.y + h4.z * s4.z + h4.w * s4.w;
#pragma unroll
        for (int off = 1; off < 64; off <<= 1) pv += __shfl_xor(pv, off, 64);
        if (lane == 0) out[p * BQ + row] = pv;
    }
}

extern "C" void kernel_launch(void* const* d_in, const int* in_sizes, int n_in,
                              void* d_out, int out_size, void* d_ws, size_t ws_size,
                              hipStream_t stream)
{
    const float* emb     = (const float*)d_in[0];
    const float* emb_var = (const float*)d_in[1];
    const float* nW      = (const float*)d_in[2];
    const float* nWb     = (const float*)d_in[3];
    const float* nu      = (const float*)d_in[4];
    const float* nub     = (const float*)d_in[5];
    const float* nvW     = (const float*)d_in[6];
    const float* nvWb    = (const float*)d_in[7];
    const float* nvu     = (const float*)d_in[8];
    const float* nvub    = (const float*)d_in[9];
    const float* p1W     = (const float*)d_in[10];
    const float* p1b     = (const float*)d_in[11];
    const float* p2W     = (const float*)d_in[12];
    const float* p2b     = (const float*)d_in[13];
    const float* ln_a    = (const float*)d_in[14];
    const float* ln_b    = (const float*)d_in[15];
    const float* Wih     = (const float*)d_in[16];
    const float* Whh     = (const float*)d_in[17];
    const float* bih     = (const float*)d_in[18];
    const float* bhh     = (const float*)d_in[19];
    const int* q_left    = (const int*)d_in[20];
    const int* q_right   = (const int*)d_in[21];
    const int* s_left    = (const int*)d_in[22];
    const int* s_right   = (const int*)d_in[23];

    float* ws = (float*)d_ws;
    size_t o = 0;
    float* WcatT    = ws + o; o += (size_t)KTOT * G4;       // 1,572,864
    float* p1WT     = ws + o; o += FOURD * TWOD;            // 131,072
    float* p2WT     = ws + o; o += FOURD * TWOD;            // 131,072
    float* nWT      = ws + o; o += TWOD * DD;               // 32,768
    float* nvWT     = ws + o; o += TWOD * DD;               // 32,768
    float* query    = ws + o; o += (size_t)2 * BQ * TWOD;   // 2,097,152 (reused as hfin)
    float* supportB = ws + o; o += 2 * FEWN * TWOD;         // 2,560
    float* qg       = ws + o; o += (size_t)2 * BQ * TWOD;   // 2,097,152
    float* sg       = ws + o; o += 2 * FEWN * TWOD;         // 2,560
    float* hr       = ws + o; o += (size_t)2 * BQ * FOURD;  // 4,194,304
    float* cst      = ws + o; o += (size_t)2 * BQ * FOURD;  // 4,194,304
    float* h512     = ws + o; o += (size_t)2 * BQ * FOURD;  // 4,194,304
    float* hfin     = query;                                // total ~74.7 MB

    // zero LSTM state (hr and cst are contiguous)
    hipMemsetAsync(hr, 0, (size_t)2 * BQ * FOURD * 2 * sizeof(float), stream);

    k_transpose<<<dim3(1024), dim3(256), 0, stream>>>(Wih, Whh, p1W, p2W, nW, nvW,
                                                      WcatT, p1WT, p2WT, nWT, nvWT);
    k_neighbor<<<dim3(2 * BQ + 2 * FEWN, 2), dim3(256), 0, stream>>>(
        emb, emb_var, nWT, nWb, nu, nub, nvWT, nvWb, nvu, nvub,
        q_left, q_right, s_left, s_right, query, supportB);
    k_supenc<8><<<dim3(2 * BQ / 8), dim3(256), 0, stream>>>(query, qg, p1WT, p1b, p2WT, p2b, ln_a, ln_b);
    k_supenc<1><<<dim3(2 * FEWN), dim3(256), 0, stream>>>(supportB, sg, p1WT, p1b, p2WT, p2b, ln_a, ln_b);
    for (int s = 0; s < 4; ++s) {
        k_lstm_gates<<<dim3(BQ / 32, 2), dim3(512), 0, stream>>>(qg, hr, cst, h512, WcatT, bih, bhh);
        k_lstm_attn<<<dim3(BQ / 32, 2), dim3(256), 0, stream>>>(qg, h512, sg, hr, hfin);
    }
    k_score<<<dim3(BQ / 32, 2), dim3(256), 0, stream>>>(hfin, sg, (float*)d_out);
}

// Round 2
// 1042.795 us; speedup vs baseline: 3.5486x; 3.5486x over previous
//
#include <hip/hip_runtime.h>
#include <math.h>

#define DD    128
#define TWOD  256
#define FOURD 512
#define NBN   30
#define BQ    4096
#define FEWN  5
#define KTOT  768    // 256 (query) + 256 (h) + 256 (r)
#define NGATE 1024   // 256 live units x 4 gates (units 256..511 are dead)
#define ULIVE 256

typedef short bf16x8 __attribute__((ext_vector_type(8)));
typedef float f32x4 __attribute__((ext_vector_type(4)));

__device__ __forceinline__ float sigmoidf_(float x) { return 1.0f / (1.0f + expf(-x)); }

__device__ __forceinline__ unsigned short f2bf(float f) {
    unsigned int u = __float_as_uint(f);
    unsigned int r = (u + 0x7fffu + ((u >> 16) & 1u)) >> 16;
    return (unsigned short)r;
}

__device__ __forceinline__ void gload_lds16(const void* g, void* l) {
    __builtin_amdgcn_global_load_lds((const __attribute__((address_space(1))) unsigned int*)g,
                                     (__attribute__((address_space(3))) unsigned int*)l,
                                     16, 0, 0);
}

// ---------------- K0: one-time weight prep -------------------------------------
// fp32 transposes for supenc/neighbor + bf16 reordered LSTM weight matrix:
//   Wbf[n][k], n = 64*(u>>4) + 16*g + (u&15), u in [0,256), k in [0,768)
__global__ __launch_bounds__(256) void k_prep(
    const float* __restrict__ Wih, const float* __restrict__ Whh,
    const float* __restrict__ bih, const float* __restrict__ bhh,
    const float* __restrict__ p1W, const float* __restrict__ p2W,
    const float* __restrict__ nW, const float* __restrict__ nvW,
    unsigned short* __restrict__ Wbf, float* __restrict__ biasR,
    float* __restrict__ p1WT, float* __restrict__ p2WT,
    float* __restrict__ nWT, float* __restrict__ nvWT)
{
    int idx = blockIdx.x * 256 + threadIdx.x;
    int stride = gridDim.x * 256;
    for (int i = idx; i < NGATE * KTOT; i += stride) {
        int n = i / KTOT, k = i - n * KTOT;
        int blk = n >> 6, rem = n & 63;
        int g = rem >> 4, ul = rem & 15;
        int u = blk * 16 + ul;
        int srcrow = g * 512 + u;
        float v = (k < TWOD) ? Wih[srcrow * TWOD + k] : Whh[srcrow * FOURD + (k - TWOD)];
        Wbf[i] = f2bf(v);
    }
    for (int n = idx; n < NGATE; n += stride) {
        int blk = n >> 6, rem = n & 63;
        int g = rem >> 4, ul = rem & 15;
        int u = blk * 16 + ul;
        int srcrow = g * 512 + u;
        biasR[n] = bih[srcrow] + bhh[srcrow];
    }
    for (int i = idx; i < FOURD * TWOD; i += stride) {
        int o = i / TWOD, j = i % TWOD;
        p1WT[j * FOURD + o] = p1W[o * TWOD + j];
    }
    for (int i = idx; i < TWOD * FOURD; i += stride) {
        int o = i / FOURD, j = i % FOURD;
        p2WT[j * TWOD + o] = p2W[o * FOURD + j];
    }
    for (int i = idx; i < DD * TWOD; i += stride) {
        int o = i / TWOD, j = i % TWOD;
        nWT[j * DD + o]  = nW[o * TWOD + j];
        nvWT[j * DD + o] = nvW[o * TWOD + j];
    }
}

// ---------------- K1: neighbor encoder (gather + attention + pool + tanh) ------
__global__ __launch_bounds__(256) void k_neighbor(
    const float* __restrict__ emb, const float* __restrict__ emb_var,
    const float* __restrict__ nWT, const float* __restrict__ nWb,
    const float* __restrict__ nu, const float* __restrict__ nub,
    const float* __restrict__ nvWT, const float* __restrict__ nvWb,
    const float* __restrict__ nvu, const float* __restrict__ nvub,
    const int* __restrict__ q_left, const int* __restrict__ q_right,
    const int* __restrict__ s_left, const int* __restrict__ s_right,
    float* __restrict__ query, float* __restrict__ support)
{
    const int row = blockIdx.x;
    const int p   = blockIdx.y;
    const int tid = threadIdx.x;

    const int* conn; float* dst;
    if (row < BQ)                { conn = q_left  + row * (NBN * 2);              dst = query   + ((size_t)p * BQ  + row) * TWOD; }
    else if (row < 2 * BQ)       { conn = q_right + (row - BQ) * (NBN * 2);       dst = query   + ((size_t)p * BQ  + (row - BQ)) * TWOD + DD; }
    else if (row < 2 * BQ + FEWN){ conn = s_left  + (row - 2 * BQ) * (NBN * 2);   dst = support + ((size_t)p * FEWN + (row - 2 * BQ)) * TWOD; }
    else                         { conn = s_right + (row - 2 * BQ - FEWN) * (NBN * 2);
                                   dst = support + ((size_t)p * FEWN + (row - 2 * BQ - FEWN)) * TWOD + DD; }

    const float* tbl = p ? emb_var : emb;
    const float* WT  = p ? nvWT : nWT;
    const float* Wb  = p ? nvWb : nWb;
    const float* uu  = p ? nvu  : nu;
    const float  ubb = p ? nvub[0] : nub[0];

    __shared__ int   sidx[NBN * 2];
    __shared__ float cat[32][260];
    __shared__ float entE[NBN][DD];
    __shared__ float scoresP[4][32];
    __shared__ float scores[32];
    __shared__ float att[NBN];

    if (tid < NBN * 2) sidx[tid] = conn[tid];
    __syncthreads();

    for (int k = 0; k < 32; ++k) {
        int j = tid;
        float v = 0.f;
        if (k < NBN) {
            int r = (j < DD) ? sidx[2 * k] : sidx[2 * k + 1];
            v = tbl[(size_t)r * DD + (j & (DD - 1))];
        }
        cat[k][j] = v;
    }
    for (int it = 0; it < 15; ++it) {
        int idx = it * 256 + tid;
        int k = idx >> 7, j = idx & 127;
        entE[k][j] = emb[(size_t)sidx[2 * k + 1] * DD + j];
    }
    __syncthreads();

    const int iq = tid >> 3;
    const int kg = tid & 7;
    const int k0 = kg * 4;
    float acc[4][4] = {};

    for (int j = 0; j < TWOD; j += 4) {
        float w[4][4] __attribute__((aligned(16)));
        *(float4*)w[0] = *(const float4*)(WT + (j + 0) * DD + iq * 4);
        *(float4*)w[1] = *(const float4*)(WT + (j + 1) * DD + iq * 4);
        *(float4*)w[2] = *(const float4*)(WT + (j + 2) * DD + iq * 4);
        *(float4*)w[3] = *(const float4*)(WT + (j + 3) * DD + iq * 4);
        float c[4][4] __attribute__((aligned(16)));
        *(float4*)c[0] = *(const float4*)&cat[k0 + 0][j];
        *(float4*)c[1] = *(const float4*)&cat[k0 + 1][j];
        *(float4*)c[2] = *(const float4*)&cat[k0 + 2][j];
        *(float4*)c[3] = *(const float4*)&cat[k0 + 3][j];
#pragma unroll
        for (int kk = 0; kk < 4; ++kk)
#pragma unroll
            for (int jj = 0; jj < 4; ++jj)
#pragma unroll
                for (int ii = 0; ii < 4; ++ii)
                    acc[ii][kk] += w[jj][ii] * c[kk][jj];
    }

    float pa[4] = {0.f, 0.f, 0.f, 0.f};
#pragma unroll
    for (int ii = 0; ii < 4; ++ii) {
        int i = iq * 4 + ii;
        float wbi = Wb[i], ui = uu[i];
#pragma unroll
        for (int kk = 0; kk < 4; ++kk)
            pa[kk] += ui * tanhf(acc[ii][kk] + wbi);
    }
#pragma unroll
    for (int off = 8; off < 64; off <<= 1)
#pragma unroll
        for (int kk = 0; kk < 4; ++kk)
            pa[kk] += __shfl_xor(pa[kk], off, 64);
    const int wv = tid >> 6, lane = tid & 63;
    if (lane < 8) {
#pragma unroll
        for (int kk = 0; kk < 4; ++kk) scoresP[wv][lane * 4 + kk] = pa[kk];
    }
    __syncthreads();
    if (tid < 32)
        scores[tid] = ubb + scoresP[0][tid] + scoresP[1][tid] + scoresP[2][tid] + scoresP[3][tid];
    __syncthreads();
    if (tid == 0) {
        float mx = -1e30f;
        for (int k = 0; k < NBN; ++k) mx = fmaxf(mx, scores[k]);
        float sum = 0.f;
        for (int k = 0; k < NBN; ++k) { float e = expf(scores[k] - mx); att[k] = e; sum += e; }
        float inv = 1.f / sum;
        for (int k = 0; k < NBN; ++k) att[k] *= inv;
    }
    __syncthreads();
    if (tid < DD) {
        float pooled = 0.f;
        for (int k = 0; k < NBN; ++k) pooled += att[k] * entE[k][tid];
        dst[tid] = tanhf(pooled);
    }
}

// ---------------- K2: support encoder (MLP + residual + layernorm ddof=1) ------
template <int RPB>
__global__ __launch_bounds__(256) void k_supenc(
    const float* __restrict__ xin, float* __restrict__ xout,
    unsigned short* __restrict__ abf,   // optional bf16 copy into Abf[:, 0:256]
    const float* __restrict__ p1WT, const float* __restrict__ p1b,
    const float* __restrict__ p2WT, const float* __restrict__ p2b,
    const float* __restrict__ ln_a, const float* __restrict__ ln_b)
{
    const int tid = threadIdx.x;
    const int r0 = blockIdx.x * RPB;
    __shared__ float X[RPB][TWOD];
    __shared__ float H1[RPB][FOURD];
    __shared__ float red[4][RPB][2];
    __shared__ float muv[RPB], sgv[RPB];

    for (int idx = tid; idx < RPB * TWOD; idx += 256) {
        int r = idx >> 8, j = idx & 255;
        X[r][j] = xin[(size_t)(r0 + r) * TWOD + j];
    }
    __syncthreads();

    {
        float acc[RPB][2] = {};
        for (int j = 0; j < TWOD; j += 4) {
            float w0[4], w1[4];
#pragma unroll
            for (int jj = 0; jj < 4; ++jj) {
                w0[jj] = p1WT[(j + jj) * FOURD + tid];
                w1[jj] = p1WT[(j + jj) * FOURD + tid + 256];
            }
#pragma unroll
            for (int r = 0; r < RPB; ++r) {
                float x[4] __attribute__((aligned(16)));
                *(float4*)x = *(const float4*)&X[r][j];
#pragma unroll
                for (int jj = 0; jj < 4; ++jj) {
                    acc[r][0] += x[jj] * w0[jj];
                    acc[r][1] += x[jj] * w1[jj];
                }
            }
        }
        float b0 = p1b[tid], b1 = p1b[tid + 256];
#pragma unroll
        for (int r = 0; r < RPB; ++r) {
            H1[r][tid]       = fmaxf(acc[r][0] + b0, 0.f);
            H1[r][tid + 256] = fmaxf(acc[r][1] + b1, 0.f);
        }
    }
    __syncthreads();

    float z[RPB];
    {
        float acc[RPB] = {};
        for (int j = 0; j < FOURD; j += 4) {
            float w[4];
#pragma unroll
            for (int jj = 0; jj < 4; ++jj) w[jj] = p2WT[(j + jj) * TWOD + tid];
#pragma unroll
            for (int r = 0; r < RPB; ++r) {
                float h[4] __attribute__((aligned(16)));
                *(float4*)h = *(const float4*)&H1[r][j];
#pragma unroll
                for (int jj = 0; jj < 4; ++jj) acc[r] += h[jj] * w[jj];
            }
        }
        float b = p2b[tid];
#pragma unroll
        for (int r = 0; r < RPB; ++r) z[r] = acc[r] + b + X[r][tid];
    }
    {
        float s[RPB], ss[RPB];
#pragma unroll
        for (int r = 0; r < RPB; ++r) { s[r] = z[r]; ss[r] = z[r] * z[r]; }
#pragma unroll
        for (int off = 1; off < 64; off <<= 1)
#pragma unroll
            for (int r = 0; r < RPB; ++r) {
                s[r]  += __shfl_xor(s[r],  off, 64);
                ss[r] += __shfl_xor(ss[r], off, 64);
            }
        const int wv = tid >> 6, lane = tid & 63;
        if (lane == 0) {
#pragma unroll
            for (int r = 0; r < RPB; ++r) { red[wv][r][0] = s[r]; red[wv][r][1] = ss[r]; }
        }
        __syncthreads();
        if (tid < RPB) {
            float st  = red[0][tid][0] + red[1][tid][0] + red[2][tid][0] + red[3][tid][0];
            float sst = red[0][tid][1] + red[1][tid][1] + red[2][tid][1] + red[3][tid][1];
            float mu  = st / (float)TWOD;
            float var = fmaxf((sst - (float)TWOD * mu * mu) / ((float)TWOD - 1.f), 0.f);
            muv[tid] = mu; sgv[tid] = sqrtf(var);
        }
        __syncthreads();
    }
#pragma unroll
    for (int r = 0; r < RPB; ++r) {
        float o = (z[r] - muv[r]) / (sgv[r] + 1e-3f) * ln_a[tid] + ln_b[tid];
        xout[(size_t)(r0 + r) * TWOD + tid] = o;
        if (abf) abf[(size_t)(r0 + r) * KTOT + tid] = f2bf(o);
    }
}

// ---------------- K4a: LSTM gates via bf16 MFMA, fused cell update -------------
// C = Abf[8192 x 768] * Wbf^T[768 x 1024]; 128x128 tile, 4 waves, 16x16x32 mfma.
// Gate interleave n = 64*(u>>4) + 16*g + (u&15): thread's 4 ni-frags = gates i,f,g,o.
__global__ __launch_bounds__(256) void k_lstm_mfma(
    const unsigned short* __restrict__ Abf,
    const unsigned short* __restrict__ Wbf,
    const float* __restrict__ biasR,
    float* __restrict__ cst, float* __restrict__ hbuf)
{
    __shared__ __align__(16) unsigned short As[128 * 32];
    __shared__ __align__(16) unsigned short Bs[128 * 32];
    const int tid  = threadIdx.x;
    const int wave = tid >> 6, lane = tid & 63;
    const int quad = lane >> 4, m15 = lane & 15;
    const int m0 = blockIdx.x * 128;
    const int n0 = blockIdx.y * 128;
    const int wm = wave >> 1, wn = wave & 1;
    const int lrow = lane >> 2, lslot = lane & 3;

    f32x4 acc[4][4] = {};   // [mi][gate]

    for (int kt = 0; kt < KTOT / 32; ++kt) {
        const int k0 = kt * 32;
        __syncthreads();
#pragma unroll
        for (int t = 0; t < 2; ++t) {
            int c = wave * 2 + t;
            int row = c * 16 + lrow;
            int kg = lslot ^ ((row >> 1) & 3);           // XOR swizzle (2-way = free)
            gload_lds16(Abf + (size_t)(m0 + row) * KTOT + k0 + kg * 8, As + c * 512);
            gload_lds16(Wbf + (size_t)(n0 + row) * KTOT + k0 + kg * 8, Bs + c * 512);
        }
        __syncthreads();

        bf16x8 fa[4], fb[4];
#pragma unroll
        for (int mi = 0; mi < 4; ++mi) {
            int ra = wm * 64 + mi * 16 + m15;
            int sa = quad ^ ((ra >> 1) & 3);
            fa[mi] = *(const bf16x8*)(As + ra * 32 + sa * 8);
            int rb = wn * 64 + mi * 16 + m15;
            int sb = quad ^ ((rb >> 1) & 3);
            fb[mi] = *(const bf16x8*)(Bs + rb * 32 + sb * 8);
        }
#pragma unroll
        for (int mi = 0; mi < 4; ++mi)
#pragma unroll
            for (int ni = 0; ni < 4; ++ni)
                acc[mi][ni] = __builtin_amdgcn_mfma_f32_16x16x32_bf16(fa[mi], fb[ni], acc[mi][ni], 0, 0, 0);
    }

    // epilogue: fused gates -> cell update. u = (n0 + wn*64)/4 + m15
    const int u = ((n0 + wn * 64) >> 2) + m15;
    float bg[4];
#pragma unroll
    for (int g = 0; g < 4; ++g) bg[g] = biasR[n0 + wn * 64 + g * 16 + m15];
#pragma unroll
    for (int mi = 0; mi < 4; ++mi) {
#pragma unroll
        for (int r = 0; r < 4; ++r) {
            int gm = m0 + wm * 64 + mi * 16 + quad * 4 + r;
            size_t cidx = (size_t)gm * ULIVE + u;
            float pi = acc[mi][0][r] + bg[0];
            float pf = acc[mi][1][r] + bg[1];
            float pg = acc[mi][2][r] + bg[2];
            float po = acc[mi][3][r] + bg[3];
            float cn = sigmoidf_(pf) * cst[cidx] + sigmoidf_(pi) * tanhf(pg);
            cst[cidx]  = cn;
            hbuf[cidx] = sigmoidf_(po) * tanhf(cn);
        }
    }
}

// ---------------- K4b: h, attention over support, write bf16 h|r ---------------
__global__ __launch_bounds__(256) void k_lstm_attn(
    const float* __restrict__ qg, const float* __restrict__ hbuf,
    const float* __restrict__ sg, unsigned short* __restrict__ Abf,
    float* __restrict__ hfin)
{
    const int tid = threadIdx.x;
    const int p   = blockIdx.y;
    const int wv = tid >> 6, lane = tid & 63;
    __shared__ float sgl[FEWN][TWOD];
    for (int idx = tid; idx < FEWN * TWOD; idx += 256)
        sgl[idx >> 8][idx & 255] = sg[p * FEWN * TWOD + idx];
    __syncthreads();
    const int j0 = lane * 4;
    for (int rr = 0; rr < 8; ++rr) {
        int row = blockIdx.x * 32 + wv * 8 + rr;
        size_t g = (size_t)p * BQ + row;
        float4 q4 = *(const float4*)(qg + g * TWOD + j0);
        float4 t4 = *(const float4*)(hbuf + g * ULIVE + j0);
        float h[4] __attribute__((aligned(16))) = {q4.x + t4.x, q4.y + t4.y, q4.z + t4.z, q4.w + t4.w};
        float sv[FEWN][4] __attribute__((aligned(16)));
        float pa[FEWN];
#pragma unroll
        for (int f = 0; f < FEWN; ++f) {
            *(float4*)sv[f] = *(const float4*)&sgl[f][j0];
            pa[f] = h[0] * sv[f][0] + h[1] * sv[f][1] + h[2] * sv[f][2] + h[3] * sv[f][3];
        }
#pragma unroll
        for (int off = 1; off < 64; off <<= 1)
#pragma unroll
            for (int f = 0; f < FEWN; ++f) pa[f] += __shfl_xor(pa[f], off, 64);
        float mx = pa[0];
#pragma unroll
        for (int f = 1; f < FEWN; ++f) mx = fmaxf(mx, pa[f]);
        float sum = 0.f, e[FEWN];
#pragma unroll
        for (int f = 0; f < FEWN; ++f) { e[f] = expf(pa[f] - mx); sum += e[f]; }
        float inv = 1.f / sum;
        float r4[4] __attribute__((aligned(16))) = {0.f, 0.f, 0.f, 0.f};
#pragma unroll
        for (int f = 0; f < FEWN; ++f) {
            float a = e[f] * inv;
#pragma unroll
            for (int q = 0; q < 4; ++q) r4[q] += a * sv[f][q];
        }
        // write bf16 [h | r] into Abf cols 256:768, fp32 h into hfin
        unsigned short tb[4] __attribute__((aligned(8)));
#pragma unroll
        for (int q = 0; q < 4; ++q) tb[q] = f2bf(h[q]);
        *(uint2*)(Abf + g * KTOT + TWOD + j0) = *(uint2*)tb;
#pragma unroll
        for (int q = 0; q < 4; ++q) tb[q] = f2bf(r4[q]);
        *(uint2*)(Abf + g * KTOT + FOURD + j0) = *(uint2*)tb;
        *(float4*)(hfin + g * TWOD + j0) = *(float4*)h;
    }
}

// ---------------- K5: final scores ---------------------------------------------
__global__ __launch_bounds__(256) void k_score(
    const float* __restrict__ hfin, const float* __restrict__ sg, float* __restrict__ out)
{
    const int tid = threadIdx.x;
    const int p   = blockIdx.y;
    __shared__ float sm[TWOD];
    if (tid < TWOD) {
        const float* s = sg + p * FEWN * TWOD + tid;
        sm[tid] = (s[0] + s[TWOD] + s[2 * TWOD] + s[3 * TWOD] + s[4 * TWOD]) / 5.0f;
    }
    __syncthreads();
    const int wv = tid >> 6, lane = tid & 63;
    const int j0 = lane * 4;
    for (int rr = 0; rr < 8; ++rr) {
        int row = blockIdx.x * 32 + wv * 8 + rr;
        const float* h = hfin + ((size_t)p * BQ + row) * TWOD + j0;
        float4 h4 = *(const float4*)h;
        float4 s4 = *(const float4*)&sm[j0];
        float pv = h4.x * s4.x + h4.y * s4.y + h4.z * s4.z + h4.w * s4.w;
#pragma unroll
        for (int off = 1; off < 64; off <<= 1) pv += __shfl_xor(pv, off, 64);
        if (lane == 0) out[p * BQ + row] = pv;
    }
}

extern "C" void kernel_launch(void* const* d_in, const int* in_sizes, int n_in,
                              void* d_out, int out_size, void* d_ws, size_t ws_size,
                              hipStream_t stream)
{
    const float* emb     = (const float*)d_in[0];
    const float* emb_var = (const float*)d_in[1];
    const float* nW      = (const float*)d_in[2];
    const float* nWb     = (const float*)d_in[3];
    const float* nu      = (const float*)d_in[4];
    const float* nub     = (const float*)d_in[5];
    const float* nvW     = (const float*)d_in[6];
    const float* nvWb    = (const float*)d_in[7];
    const float* nvu     = (const float*)d_in[8];
    const float* nvub    = (const float*)d_in[9];
    const float* p1W     = (const float*)d_in[10];
    const float* p1b     = (const float*)d_in[11];
    const float* p2W     = (const float*)d_in[12];
    const float* p2b     = (const float*)d_in[13];
    const float* ln_a    = (const float*)d_in[14];
    const float* ln_b    = (const float*)d_in[15];
    const float* Wih     = (const float*)d_in[16];
    const float* Whh     = (const float*)d_in[17];
    const float* bih     = (const float*)d_in[18];
    const float* bhh     = (const float*)d_in[19];
    const int* q_left    = (const int*)d_in[20];
    const int* q_right   = (const int*)d_in[21];
    const int* s_left    = (const int*)d_in[22];
    const int* s_right   = (const int*)d_in[23];

    float* ws = (float*)d_ws;
    size_t o = 0;
    float* p1WT     = ws + o; o += FOURD * TWOD;             // 131,072
    float* p2WT     = ws + o; o += FOURD * TWOD;             // 131,072
    float* nWT      = ws + o; o += TWOD * DD;                // 32,768
    float* nvWT     = ws + o; o += TWOD * DD;                // 32,768
    float* biasR    = ws + o; o += NGATE;                    // 1,024
    float* query    = ws + o; o += (size_t)2 * BQ * TWOD;    // 2,097,152 (reused as hfin)
    float* supportB = ws + o; o += 2 * FEWN * TWOD;          // 2,560
    float* qg       = ws + o; o += (size_t)2 * BQ * TWOD;    // 2,097,152
    float* sg       = ws + o; o += 2 * FEWN * TWOD;          // 2,560
    float* cst      = ws + o; o += (size_t)2 * BQ * ULIVE;   // 2,097,152
    float* hbuf     = ws + o; o += (size_t)2 * BQ * ULIVE;   // 2,097,152
    unsigned short* Wbf = (unsigned short*)(ws + o); o += (size_t)NGATE * KTOT / 2;     // 393,216 f
    unsigned short* Abf = (unsigned short*)(ws + o); o += (size_t)2 * BQ * KTOT / 2;    // 3,145,728 f
    float* hfin     = query;                                 // total ~49 MB

    // zero LSTM state: c = 0, and Abf h|r region = 0 (bf16 zero == 0x0000)
    hipMemsetAsync(cst, 0, (size_t)2 * BQ * ULIVE * sizeof(float), stream);
    hipMemsetAsync(Abf, 0, (size_t)2 * BQ * KTOT * sizeof(unsigned short), stream);

    k_prep<<<dim3(1024), dim3(256), 0, stream>>>(Wih, Whh, bih, bhh, p1W, p2W, nW, nvW,
                                                 Wbf, biasR, p1WT, p2WT, nWT, nvWT);
    k_neighbor<<<dim3(2 * BQ + 2 * FEWN, 2), dim3(256), 0, stream>>>(
        emb, emb_var, nWT, nWb, nu, nub, nvWT, nvWb, nvu, nvub,
        q_left, q_right, s_left, s_right, query, supportB);
    k_supenc<8><<<dim3(2 * BQ / 8), dim3(256), 0, stream>>>(query, qg, Abf, p1WT, p1b, p2WT, p2b, ln_a, ln_b);
    k_supenc<1><<<dim3(2 * FEWN), dim3(256), 0, stream>>>(supportB, sg, (unsigned short*)nullptr,
                                                          p1WT, p1b, p2WT, p2b, ln_a, ln_b);
    for (int s = 0; s < 4; ++s) {
        k_lstm_mfma<<<dim3(2 * BQ / 128, NGATE / 128), dim3(256), 0, stream>>>(Abf, Wbf, biasR, cst, hbuf);
        k_lstm_attn<<<dim3(BQ / 32, 2), dim3(256), 0, stream>>>(qg, hbuf, sg, Abf, hfin);
    }
    k_score<<<dim3(BQ / 32, 2), dim3(256), 0, stream>>>(hfin, sg, (float*)d_out);
}

// Round 3
// 797.089 us; speedup vs baseline: 4.6425x; 1.3083x over previous
//
#include <hip/hip_runtime.h>
#include <math.h>

#define DD    128
#define TWOD  256
#define FOURD 512
#define NBN   30
#define BQ    4096
#define FEWN  5
#define NSYM  200000
#define KTOT  768    // 256 (query) + 256 (h) + 256 (r)
#define NGATE 1024   // 256 live units x 4 gates (units 256..511 are dead)
#define ULIVE 256

typedef short bf16x8 __attribute__((ext_vector_type(8)));
typedef float f32x4 __attribute__((ext_vector_type(4)));

__device__ __forceinline__ float sigmoidf_(float x) { return 1.0f / (1.0f + expf(-x)); }

__device__ __forceinline__ unsigned short f2bf(float f) {
    unsigned int u = __float_as_uint(f);
    unsigned int r = (u + 0x7fffu + ((u >> 16) & 1u)) >> 16;
    return (unsigned short)r;
}

// pack 8 fp32 -> bf16x8 (round-to-nearest, ties-away: +0x8000 then truncate)
__device__ __forceinline__ bf16x8 pack8(float4 a, float4 b) {
    union { bf16x8 v; unsigned int u[4]; } r;
    r.u[0] = ((__float_as_uint(a.x) + 0x8000u) >> 16) | ((__float_as_uint(a.y) + 0x8000u) & 0xffff0000u);
    r.u[1] = ((__float_as_uint(a.z) + 0x8000u) >> 16) | ((__float_as_uint(a.w) + 0x8000u) & 0xffff0000u);
    r.u[2] = ((__float_as_uint(b.x) + 0x8000u) >> 16) | ((__float_as_uint(b.y) + 0x8000u) & 0xffff0000u);
    r.u[3] = ((__float_as_uint(b.z) + 0x8000u) >> 16) | ((__float_as_uint(b.w) + 0x8000u) & 0xffff0000u);
    return r.v;
}

__device__ __forceinline__ void gload_lds16(const void* g, void* l) {
    __builtin_amdgcn_global_load_lds((const __attribute__((address_space(1))) unsigned int*)g,
                                     (__attribute__((address_space(3))) unsigned int*)l,
                                     16, 0, 0);
}

// ---------------- K0: one-time weight prep -------------------------------------
__global__ __launch_bounds__(256) void k_prep(
    const float* __restrict__ Wih, const float* __restrict__ Whh,
    const float* __restrict__ bih, const float* __restrict__ bhh,
    const float* __restrict__ p1W, const float* __restrict__ p2W,
    const float* __restrict__ nW, const float* __restrict__ nvW,
    unsigned short* __restrict__ Wbf, float* __restrict__ biasR,
    float* __restrict__ p1WT, float* __restrict__ p2WT,
    unsigned short* __restrict__ Nbf)
{
    int idx = blockIdx.x * 256 + threadIdx.x;
    int stride = gridDim.x * 256;
    for (int i = idx; i < NGATE * KTOT; i += stride) {
        int n = i / KTOT, k = i - n * KTOT;
        int blk = n >> 6, rem = n & 63;
        int g = rem >> 4, ul = rem & 15;
        int u = blk * 16 + ul;
        int srcrow = g * 512 + u;
        float v = (k < TWOD) ? Wih[srcrow * TWOD + k] : Whh[srcrow * FOURD + (k - TWOD)];
        Wbf[i] = f2bf(v);
    }
    for (int n = idx; n < NGATE; n += stride) {
        int blk = n >> 6, rem = n & 63;
        int g = rem >> 4, ul = rem & 15;
        int u = blk * 16 + ul;
        int srcrow = g * 512 + u;
        biasR[n] = bih[srcrow] + bhh[srcrow];
    }
    for (int i = idx; i < FOURD * TWOD; i += stride) {
        int o = i / TWOD, j = i % TWOD;
        p1WT[j * FOURD + o] = p1W[o * TWOD + j];
    }
    for (int i = idx; i < TWOD * FOURD; i += stride) {
        int o = i / FOURD, j = i % FOURD;
        p2WT[j * TWOD + o] = p2W[o * FOURD + j];
    }
    // bf16 copies of nW / nvW, both [128][256] row-major (already [n][k])
    for (int i = idx; i < 2 * DD * TWOD; i += stride) {
        float v = (i < DD * TWOD) ? nW[i] : nvW[i - DD * TWOD];
        Nbf[i] = f2bf(v);
    }
}

// ---------------- K1: neighbor encoder via MFMA --------------------------------
// Per (row,path) unit: S[32x128] = cat[32x256] * W^T, cat gathered straight from
// global into A-fragments (lane m15 = neighbor row). B held in 128 VGPRs/wave.
// Then tanh+u-dot -> softmax over 30 -> pool emb[ent] rows -> tanh -> dst.
#define RUN 2   // row-units per block
__global__ __launch_bounds__(256) void k_neighbor_mfma(
    const float* __restrict__ emb, const float* __restrict__ emb_var,
    const unsigned short* __restrict__ Nbf,
    const float* __restrict__ nWb, const float* __restrict__ nu,
    const float* __restrict__ nvWb, const float* __restrict__ nvu,
    const int* __restrict__ q_left, const int* __restrict__ q_right,
    const int* __restrict__ s_left, const int* __restrict__ s_right,
    float* __restrict__ query, float* __restrict__ support)
{
    const int p    = blockIdx.y;
    const int tid  = threadIdx.x;
    const int wave = tid >> 6, lane = tid & 63;
    const int quad = lane >> 4, m15 = lane & 15;
    const int wm = wave >> 1, wn = wave & 1;

    const float* tbl = p ? emb_var : emb;
    const float* Wb  = p ? nvWb : nWb;
    const float* uu  = p ? nvu  : nu;
    const unsigned short* Bw = Nbf + (size_t)p * DD * TWOD;

    // B fragments: 4 n-tiles x 8 k-steps, resident in VGPRs for the whole block
    bf16x8 Bf[4][8];
    float nb[4], un[4];
#pragma unroll
    for (int t = 0; t < 4; ++t) {
        int n = wn * 64 + t * 16 + m15;
#pragma unroll
        for (int kt = 0; kt < 8; ++kt)
            Bf[t][kt] = *(const bf16x8*)(Bw + n * TWOD + kt * 32 + quad * 8);
        nb[t] = Wb[n];
        un[t] = uu[n];
    }

    __shared__ int   sidx[RUN][64];     // [unit][2k+e], k>=30 -> NSYM (zero row)
    __shared__ float scoresP[2][32];
    __shared__ float att[32];
    __shared__ float poolP[DD];

    // fill neighbor indices for all units
    if (tid < RUN * 64) {
        int r = tid >> 6, i = tid & 63;
        int u = blockIdx.x * RUN + r;
        const int* conn;
        if (u < BQ)                 conn = q_left  + u * (NBN * 2);
        else if (u < 2 * BQ)        conn = q_right + (u - BQ) * (NBN * 2);
        else if (u < 2 * BQ + FEWN) conn = s_left  + (u - 2 * BQ) * (NBN * 2);
        else                        conn = s_right + (u - 2 * BQ - FEWN) * (NBN * 2);
        sidx[r][i] = (i < NBN * 2) ? conn[i] : NSYM;
    }
    __syncthreads();

    for (int r = 0; r < RUN; ++r) {
        const int u = blockIdx.x * RUN + r;
        float* dst;
        if (u < BQ)                 dst = query   + ((size_t)p * BQ + u) * TWOD;
        else if (u < 2 * BQ)        dst = query   + ((size_t)p * BQ + (u - BQ)) * TWOD + DD;
        else if (u < 2 * BQ + FEWN) dst = support + ((size_t)p * FEWN + (u - 2 * BQ)) * TWOD;
        else                        dst = support + ((size_t)p * FEWN + (u - 2 * BQ - FEWN)) * TWOD + DD;

        // ---- MFMA: gather A-fragments from global, accumulate S ----
        const int m = wm * 16 + m15;
        const int rel = sidx[r][2 * m], ent = sidx[r][2 * m + 1];
        const float* rowrel = tbl + (size_t)rel * DD;
        const float* rowent = tbl + (size_t)ent * DD;
        f32x4 acc[4] = {};
#pragma unroll
        for (int kt = 0; kt < 8; ++kt) {
            const float* src = (kt < 4) ? rowrel : rowent;
            const int c = (kt & 3) * 32 + quad * 8;
            float4 x0 = *(const float4*)(src + c);
            float4 x1 = *(const float4*)(src + c + 4);
            bf16x8 af = pack8(x0, x1);
#pragma unroll
            for (int t = 0; t < 4; ++t)
                acc[t] = __builtin_amdgcn_mfma_f32_16x16x32_bf16(af, Bf[t][kt], acc[t], 0, 0, 0);
        }

        // ---- epilogue: a[m] = sum_n u[n]*tanh(S[m][n] + b[n]) ----
        float part[4];
#pragma unroll
        for (int rr = 0; rr < 4; ++rr) {
            float s = 0.f;
#pragma unroll
            for (int t = 0; t < 4; ++t) s += un[t] * tanhf(acc[t][rr] + nb[t]);
            part[rr] = s;
        }
#pragma unroll
        for (int off = 1; off < 16; off <<= 1)
#pragma unroll
            for (int rr = 0; rr < 4; ++rr) part[rr] += __shfl_xor(part[rr], off, 64);
        if (m15 == 0) {
#pragma unroll
            for (int rr = 0; rr < 4; ++rr) scoresP[wn][wm * 16 + quad * 4 + rr] = part[rr];
        }
        __syncthreads();

        // ---- softmax over 30 neighbors (wave 0; nub shift cancels) ----
        if (wave == 0) {
            float sc = (lane < NBN) ? scoresP[0][lane] + scoresP[1][lane] : -1e30f;
            float mx = sc;
#pragma unroll
            for (int off = 1; off < 32; off <<= 1) mx = fmaxf(mx, __shfl_xor(mx, off, 64));
            float e = (lane < NBN) ? expf(sc - mx) : 0.f;
            float sum = e;
#pragma unroll
            for (int off = 1; off < 32; off <<= 1) sum += __shfl_xor(sum, off, 64);
            if (lane < 32) att[lane] = e / sum;
        }
        __syncthreads();

        // ---- pool emb[ent] rows with att, tanh, store ----
        {
            const int d = tid & 127;
            const int half = tid >> 7;
            float pool = 0.f;
            const int k0 = half * 15;
#pragma unroll
            for (int k = 0; k < 15; ++k)
                pool += att[k0 + k] * emb[(size_t)sidx[r][2 * (k0 + k) + 1] * DD + d];
            if (half) poolP[d] = pool;
            __syncthreads();
            if (!half) dst[d] = tanhf(pool + poolP[d]);
        }
    }
}

// ---------------- K2: support encoder (MLP + residual + layernorm ddof=1) ------
template <int RPB>
__global__ __launch_bounds__(256) void k_supenc(
    const float* __restrict__ xin, float* __restrict__ xout,
    unsigned short* __restrict__ abf,
    const float* __restrict__ p1WT, const float* __restrict__ p1b,
    const float* __restrict__ p2WT, const float* __restrict__ p2b,
    const float* __restrict__ ln_a, const float* __restrict__ ln_b)
{
    const int tid = threadIdx.x;
    const int r0 = blockIdx.x * RPB;
    __shared__ float X[RPB][TWOD];
    __shared__ float H1[RPB][FOURD];
    __shared__ float red[4][RPB][2];
    __shared__ float muv[RPB], sgv[RPB];

    for (int idx = tid; idx < RPB * TWOD; idx += 256) {
        int r = idx >> 8, j = idx & 255;
        X[r][j] = xin[(size_t)(r0 + r) * TWOD + j];
    }
    __syncthreads();

    {
        float acc[RPB][2] = {};
        for (int j = 0; j < TWOD; j += 4) {
            float w0[4], w1[4];
#pragma unroll
            for (int jj = 0; jj < 4; ++jj) {
                w0[jj] = p1WT[(j + jj) * FOURD + tid];
                w1[jj] = p1WT[(j + jj) * FOURD + tid + 256];
            }
#pragma unroll
            for (int r = 0; r < RPB; ++r) {
                float x[4] __attribute__((aligned(16)));
                *(float4*)x = *(const float4*)&X[r][j];
#pragma unroll
                for (int jj = 0; jj < 4; ++jj) {
                    acc[r][0] += x[jj] * w0[jj];
                    acc[r][1] += x[jj] * w1[jj];
                }
            }
        }
        float b0 = p1b[tid], b1 = p1b[tid + 256];
#pragma unroll
        for (int r = 0; r < RPB; ++r) {
            H1[r][tid]       = fmaxf(acc[r][0] + b0, 0.f);
            H1[r][tid + 256] = fmaxf(acc[r][1] + b1, 0.f);
        }
    }
    __syncthreads();

    float z[RPB];
    {
        float acc[RPB] = {};
        for (int j = 0; j < FOURD; j += 4) {
            float w[4];
#pragma unroll
            for (int jj = 0; jj < 4; ++jj) w[jj] = p2WT[(j + jj) * TWOD + tid];
#pragma unroll
            for (int r = 0; r < RPB; ++r) {
                float h[4] __attribute__((aligned(16)));
                *(float4*)h = *(const float4*)&H1[r][j];
#pragma unroll
                for (int jj = 0; jj < 4; ++jj) acc[r] += h[jj] * w[jj];
            }
        }
        float b = p2b[tid];
#pragma unroll
        for (int r = 0; r < RPB; ++r) z[r] = acc[r] + b + X[r][tid];
    }
    {
        float s[RPB], ss[RPB];
#pragma unroll
        for (int r = 0; r < RPB; ++r) { s[r] = z[r]; ss[r] = z[r] * z[r]; }
#pragma unroll
        for (int off = 1; off < 64; off <<= 1)
#pragma unroll
            for (int r = 0; r < RPB; ++r) {
                s[r]  += __shfl_xor(s[r],  off, 64);
                ss[r] += __shfl_xor(ss[r], off, 64);
            }
        const int wv = tid >> 6, lane = tid & 63;
        if (lane == 0) {
#pragma unroll
            for (int r = 0; r < RPB; ++r) { red[wv][r][0] = s[r]; red[wv][r][1] = ss[r]; }
        }
        __syncthreads();
        if (tid < RPB) {
            float st  = red[0][tid][0] + red[1][tid][0] + red[2][tid][0] + red[3][tid][0];
            float sst = red[0][tid][1] + red[1][tid][1] + red[2][tid][1] + red[3][tid][1];
            float mu  = st / (float)TWOD;
            float var = fmaxf((sst - (float)TWOD * mu * mu) / ((float)TWOD - 1.f), 0.f);
            muv[tid] = mu; sgv[tid] = sqrtf(var);
        }
        __syncthreads();
    }
#pragma unroll
    for (int r = 0; r < RPB; ++r) {
        float o = (z[r] - muv[r]) / (sgv[r] + 1e-3f) * ln_a[tid] + ln_b[tid];
        xout[(size_t)(r0 + r) * TWOD + tid] = o;
        if (abf) abf[(size_t)(r0 + r) * KTOT + tid] = f2bf(o);
    }
}

// ---------------- K4a: LSTM gates via bf16 MFMA, fused cell update -------------
__global__ __launch_bounds__(256) void k_lstm_mfma(
    const unsigned short* __restrict__ Abf,
    const unsigned short* __restrict__ Wbf,
    const float* __restrict__ biasR,
    float* __restrict__ cst, float* __restrict__ hbuf)
{
    __shared__ __align__(16) unsigned short As[128 * 32];
    __shared__ __align__(16) unsigned short Bs[128 * 32];
    const int tid  = threadIdx.x;
    const int wave = tid >> 6, lane = tid & 63;
    const int quad = lane >> 4, m15 = lane & 15;
    const int m0 = blockIdx.x * 128;
    const int n0 = blockIdx.y * 128;
    const int wm = wave >> 1, wn = wave & 1;
    const int lrow = lane >> 2, lslot = lane & 3;

    f32x4 acc[4][4] = {};

    for (int kt = 0; kt < KTOT / 32; ++kt) {
        const int k0 = kt * 32;
        __syncthreads();
#pragma unroll
        for (int t = 0; t < 2; ++t) {
            int c = wave * 2 + t;
            int row = c * 16 + lrow;
            int kg = lslot ^ ((row >> 1) & 3);
            gload_lds16(Abf + (size_t)(m0 + row) * KTOT + k0 + kg * 8, As + c * 512);
            gload_lds16(Wbf + (size_t)(n0 + row) * KTOT + k0 + kg * 8, Bs + c * 512);
        }
        __syncthreads();

        bf16x8 fa[4], fb[4];
#pragma unroll
        for (int mi = 0; mi < 4; ++mi) {
            int ra = wm * 64 + mi * 16 + m15;
            int sa = quad ^ ((ra >> 1) & 3);
            fa[mi] = *(const bf16x8*)(As + ra * 32 + sa * 8);
            int rb = wn * 64 + mi * 16 + m15;
            int sb = quad ^ ((rb >> 1) & 3);
            fb[mi] = *(const bf16x8*)(Bs + rb * 32 + sb * 8);
        }
#pragma unroll
        for (int mi = 0; mi < 4; ++mi)
#pragma unroll
            for (int ni = 0; ni < 4; ++ni)
                acc[mi][ni] = __builtin_amdgcn_mfma_f32_16x16x32_bf16(fa[mi], fb[ni], acc[mi][ni], 0, 0, 0);
    }

    const int u = ((n0 + wn * 64) >> 2) + m15;
    float bg[4];
#pragma unroll
    for (int g = 0; g < 4; ++g) bg[g] = biasR[n0 + wn * 64 + g * 16 + m15];
#pragma unroll
    for (int mi = 0; mi < 4; ++mi) {
#pragma unroll
        for (int r = 0; r < 4; ++r) {
            int gm = m0 + wm * 64 + mi * 16 + quad * 4 + r;
            size_t cidx = (size_t)gm * ULIVE + u;
            float pi = acc[mi][0][r] + bg[0];
            float pf = acc[mi][1][r] + bg[1];
            float pg = acc[mi][2][r] + bg[2];
            float po = acc[mi][3][r] + bg[3];
            float cn = sigmoidf_(pf) * cst[cidx] + sigmoidf_(pi) * tanhf(pg);
            cst[cidx]  = cn;
            hbuf[cidx] = sigmoidf_(po) * tanhf(cn);
        }
    }
}

// ---------------- K4b: h, attention over support, write bf16 h|r ---------------
__global__ __launch_bounds__(256) void k_lstm_attn(
    const float* __restrict__ qg, const float* __restrict__ hbuf,
    const float* __restrict__ sg, unsigned short* __restrict__ Abf,
    float* __restrict__ hfin)
{
    const int tid = threadIdx.x;
    const int p   = blockIdx.y;
    const int wv = tid >> 6, lane = tid & 63;
    __shared__ float sgl[FEWN][TWOD];
    for (int idx = tid; idx < FEWN * TWOD; idx += 256)
        sgl[idx >> 8][idx & 255] = sg[p * FEWN * TWOD + idx];
    __syncthreads();
    const int j0 = lane * 4;
    for (int rr = 0; rr < 8; ++rr) {
        int row = blockIdx.x * 32 + wv * 8 + rr;
        size_t g = (size_t)p * BQ + row;
        float4 q4 = *(const float4*)(qg + g * TWOD + j0);
        float4 t4 = *(const float4*)(hbuf + g * ULIVE + j0);
        float h[4] __attribute__((aligned(16))) = {q4.x + t4.x, q4.y + t4.y, q4.z + t4.z, q4.w + t4.w};
        float sv[FEWN][4] __attribute__((aligned(16)));
        float pa[FEWN];
#pragma unroll
        for (int f = 0; f < FEWN; ++f) {
            *(float4*)sv[f] = *(const float4*)&sgl[f][j0];
            pa[f] = h[0] * sv[f][0] + h[1] * sv[f][1] + h[2] * sv[f][2] + h[3] * sv[f][3];
        }
#pragma unroll
        for (int off = 1; off < 64; off <<= 1)
#pragma unroll
            for (int f = 0; f < FEWN; ++f) pa[f] += __shfl_xor(pa[f], off, 64);
        float mx = pa[0];
#pragma unroll
        for (int f = 1; f < FEWN; ++f) mx = fmaxf(mx, pa[f]);
        float sum = 0.f, e[FEWN];
#pragma unroll
        for (int f = 0; f < FEWN; ++f) { e[f] = expf(pa[f] - mx); sum += e[f]; }
        float inv = 1.f / sum;
        float r4[4] __attribute__((aligned(16))) = {0.f, 0.f, 0.f, 0.f};
#pragma unroll
        for (int f = 0; f < FEWN; ++f) {
            float a = e[f] * inv;
#pragma unroll
            for (int q = 0; q < 4; ++q) r4[q] += a * sv[f][q];
        }
        unsigned short tb[4] __attribute__((aligned(8)));
#pragma unroll
        for (int q = 0; q < 4; ++q) tb[q] = f2bf(h[q]);
        *(uint2*)(Abf + g * KTOT + TWOD + j0) = *(uint2*)tb;
#pragma unroll
        for (int q = 0; q < 4; ++q) tb[q] = f2bf(r4[q]);
        *(uint2*)(Abf + g * KTOT + FOURD + j0) = *(uint2*)tb;
        *(float4*)(hfin + g * TWOD + j0) = *(float4*)h;
    }
}

// ---------------- K5: final scores ---------------------------------------------
__global__ __launch_bounds__(256) void k_score(
    const float* __restrict__ hfin, const float* __restrict__ sg, float* __restrict__ out)
{
    const int tid = threadIdx.x;
    const int p   = blockIdx.y;
    __shared__ float sm[TWOD];
    if (tid < TWOD) {
        const float* s = sg + p * FEWN * TWOD + tid;
        sm[tid] = (s[0] + s[TWOD] + s[2 * TWOD] + s[3 * TWOD] + s[4 * TWOD]) / 5.0f;
    }
    __syncthreads();
    const int wv = tid >> 6, lane = tid & 63;
    const int j0 = lane * 4;
    for (int rr = 0; rr < 8; ++rr) {
        int row = blockIdx.x * 32 + wv * 8 + rr;
        const float* h = hfin + ((size_t)p * BQ + row) * TWOD + j0;
        float4 h4 = *(const float4*)h;
        float4 s4 = *(const float4*)&sm[j0];
        float pv = h4.x * s4.x + h4.y * s4.y + h4.z * s4.z + h4.w * s4.w;
#pragma unroll
        for (int off = 1; off < 64; off <<= 1) pv += __shfl_xor(pv, off, 64);
        if (lane == 0) out[p * BQ + row] = pv;
    }
}

extern "C" void kernel_launch(void* const* d_in, const int* in_sizes, int n_in,
                              void* d_out, int out_size, void* d_ws, size_t ws_size,
                              hipStream_t stream)
{
    const float* emb     = (const float*)d_in[0];
    const float* emb_var = (const float*)d_in[1];
    const float* nW      = (const float*)d_in[2];
    const float* nWb     = (const float*)d_in[3];
    const float* nu      = (const float*)d_in[4];
    const float* nub     = (const float*)d_in[5];
    const float* nvW     = (const float*)d_in[6];
    const float* nvWb    = (const float*)d_in[7];
    const float* nvu     = (const float*)d_in[8];
    const float* nvub    = (const float*)d_in[9];
    const float* p1W     = (const float*)d_in[10];
    const float* p1b     = (const float*)d_in[11];
    const float* p2W     = (const float*)d_in[12];
    const float* p2b     = (const float*)d_in[13];
    const float* ln_a    = (const float*)d_in[14];
    const float* ln_b    = (const float*)d_in[15];
    const float* Wih     = (const float*)d_in[16];
    const float* Whh     = (const float*)d_in[17];
    const float* bih     = (const float*)d_in[18];
    const float* bhh     = (const float*)d_in[19];
    const int* q_left    = (const int*)d_in[20];
    const int* q_right   = (const int*)d_in[21];
    const int* s_left    = (const int*)d_in[22];
    const int* s_right   = (const int*)d_in[23];

    float* ws = (float*)d_ws;
    size_t o = 0;
    float* p1WT     = ws + o; o += FOURD * TWOD;
    float* p2WT     = ws + o; o += FOURD * TWOD;
    float* biasR    = ws + o; o += NGATE;
    float* query    = ws + o; o += (size_t)2 * BQ * TWOD;    // reused as hfin
    float* supportB = ws + o; o += 2 * FEWN * TWOD;
    float* qg       = ws + o; o += (size_t)2 * BQ * TWOD;
    float* sg       = ws + o; o += 2 * FEWN * TWOD;
    float* cst      = ws + o; o += (size_t)2 * BQ * ULIVE;
    float* hbuf     = ws + o; o += (size_t)2 * BQ * ULIVE;
    unsigned short* Wbf = (unsigned short*)(ws + o); o += (size_t)NGATE * KTOT / 2;
    unsigned short* Abf = (unsigned short*)(ws + o); o += (size_t)2 * BQ * KTOT / 2;
    unsigned short* Nbf = (unsigned short*)(ws + o); o += (size_t)2 * DD * TWOD / 2;
    float* hfin     = query;

    hipMemsetAsync(cst, 0, (size_t)2 * BQ * ULIVE * sizeof(float), stream);
    hipMemsetAsync(Abf, 0, (size_t)2 * BQ * KTOT * sizeof(unsigned short), stream);

    k_prep<<<dim3(1024), dim3(256), 0, stream>>>(Wih, Whh, bih, bhh, p1W, p2W, nW, nvW,
                                                 Wbf, biasR, p1WT, p2WT, Nbf);
    k_neighbor_mfma<<<dim3((2 * BQ + 2 * FEWN) / RUN, 2), dim3(256), 0, stream>>>(
        emb, emb_var, Nbf, nWb, nu, nvWb, nvu,
        q_left, q_right, s_left, s_right, query, supportB);
    k_supenc<8><<<dim3(2 * BQ / 8), dim3(256), 0, stream>>>(query, qg, Abf, p1WT, p1b, p2WT, p2b, ln_a, ln_b);
    k_supenc<1><<<dim3(2 * FEWN), dim3(256), 0, stream>>>(supportB, sg, (unsigned short*)nullptr,
                                                          p1WT, p1b, p2WT, p2b, ln_a, ln_b);
    for (int s = 0; s < 4; ++s) {
        k_lstm_mfma<<<dim3(2 * BQ / 128, NGATE / 128), dim3(256), 0, stream>>>(Abf, Wbf, biasR, cst, hbuf);
        k_lstm_attn<<<dim3(BQ / 32, 2), dim3(256), 0, stream>>>(qg, hbuf, sg, Abf, hfin);
    }
    k_score<<<dim3(BQ / 32, 2), dim3(256), 0, stream>>>(hfin, sg, (float*)d_out);
}

// Round 4
// 610.111 us; speedup vs baseline: 6.0653x; 1.3065x over previous
//
#include <hip/hip_runtime.h>
#include <math.h>

#define DD    128
#define TWOD  256
#define FOURD 512
#define NBN   30
#define BQ    4096
#define FEWN  5
#define NSYM  200000
#define KTOT  768    // 256 (query) + 256 (h) + 256 (r)
#define NGATE 1024   // 256 live units x 4 gates (units 256..511 are dead)
#define ULIVE 256
#define TOTU  (2 * BQ + 2 * FEWN)   // 8202 row-units
#define UPB   4                      // units per block (neighbor kernel)
#define PSTR  136                    // padded bf16 row stride (128 + 8)

typedef short bf16x8 __attribute__((ext_vector_type(8)));
typedef float f32x4 __attribute__((ext_vector_type(4)));

__device__ __forceinline__ float sigmoidf_(float x) { return 1.0f / (1.0f + expf(-x)); }

// fast tanh: 1 - 2/(e^{2x}+1)  (v_exp + v_rcp; |err| ~1e-6, saturates correctly)
__device__ __forceinline__ float ftanh(float x) {
    float e = __expf(2.0f * x);
    return 1.0f - 2.0f / (e + 1.0f);
}

__device__ __forceinline__ unsigned short f2bf(float f) {
    unsigned int u = __float_as_uint(f);
    unsigned int r = (u + 0x7fffu + ((u >> 16) & 1u)) >> 16;
    return (unsigned short)r;
}

__device__ __forceinline__ float bf2f(unsigned short s) {
    return __uint_as_float(((unsigned int)s) << 16);
}

// pack 8 fp32 -> bf16x8 (round-to-nearest-ish)
__device__ __forceinline__ bf16x8 pack8(float4 a, float4 b) {
    union { bf16x8 v; unsigned int u[4]; } r;
    r.u[0] = ((__float_as_uint(a.x) + 0x8000u) >> 16) | ((__float_as_uint(a.y) + 0x8000u) & 0xffff0000u);
    r.u[1] = ((__float_as_uint(a.z) + 0x8000u) >> 16) | ((__float_as_uint(a.w) + 0x8000u) & 0xffff0000u);
    r.u[2] = ((__float_as_uint(b.x) + 0x8000u) >> 16) | ((__float_as_uint(b.y) + 0x8000u) & 0xffff0000u);
    r.u[3] = ((__float_as_uint(b.z) + 0x8000u) >> 16) | ((__float_as_uint(b.w) + 0x8000u) & 0xffff0000u);
    return r.v;
}

__device__ __forceinline__ void gload_lds16(const void* g, void* l) {
    __builtin_amdgcn_global_load_lds((const __attribute__((address_space(1))) unsigned int*)g,
                                     (__attribute__((address_space(3))) unsigned int*)l,
                                     16, 0, 0);
}

// ---------------- K0: one-time weight prep -------------------------------------
__global__ __launch_bounds__(256) void k_prep(
    const float* __restrict__ Wih, const float* __restrict__ Whh,
    const float* __restrict__ bih, const float* __restrict__ bhh,
    const float* __restrict__ p1W, const float* __restrict__ p2W,
    const float* __restrict__ nW, const float* __restrict__ nvW,
    unsigned short* __restrict__ Wbf, float* __restrict__ biasR,
    float* __restrict__ p1WT, float* __restrict__ p2WT,
    unsigned short* __restrict__ Nbf)
{
    int idx = blockIdx.x * 256 + threadIdx.x;
    int stride = gridDim.x * 256;
    for (int i = idx; i < NGATE * KTOT; i += stride) {
        int n = i / KTOT, k = i - n * KTOT;
        int blk = n >> 6, rem = n & 63;
        int g = rem >> 4, ul = rem & 15;
        int u = blk * 16 + ul;
        int srcrow = g * 512 + u;
        float v = (k < TWOD) ? Wih[srcrow * TWOD + k] : Whh[srcrow * FOURD + (k - TWOD)];
        Wbf[i] = f2bf(v);
    }
    for (int n = idx; n < NGATE; n += stride) {
        int blk = n >> 6, rem = n & 63;
        int g = rem >> 4, ul = rem & 15;
        int u = blk * 16 + ul;
        int srcrow = g * 512 + u;
        biasR[n] = bih[srcrow] + bhh[srcrow];
    }
    for (int i = idx; i < FOURD * TWOD; i += stride) {
        int o = i / TWOD, j = i % TWOD;
        p1WT[j * FOURD + o] = p1W[o * TWOD + j];
    }
    for (int i = idx; i < TWOD * FOURD; i += stride) {
        int o = i / FOURD, j = i % FOURD;
        p2WT[j * TWOD + o] = p2W[o * FOURD + j];
    }
    for (int i = idx; i < 2 * DD * TWOD; i += stride) {
        float v = (i < DD * TWOD) ? nW[i] : nvW[i - DD * TWOD];
        Nbf[i] = f2bf(v);
    }
}

// ---------------- K1 v4: neighbor encoder, both paths, LDS-staged gather -------
// Block = UPB units x both paths. Waves: w>>1 = path, w&1 = n-half.
// Stage 4 row-groups (rel_e, ent_e, rel_v, ent_v) as bf16 [32][136] in LDS once;
// MFMA A-frags are single ds_read_b128; pooling reads ent_e from LDS (torch
// quirk: both paths pool emb[ent]).
__global__ __launch_bounds__(256, 2) void k_neighbor_v4(
    const float* __restrict__ emb, const float* __restrict__ emb_var,
    const unsigned short* __restrict__ Nbf,
    const float* __restrict__ nWb, const float* __restrict__ nu,
    const float* __restrict__ nvWb, const float* __restrict__ nvu,
    const int* __restrict__ q_left, const int* __restrict__ q_right,
    const int* __restrict__ s_left, const int* __restrict__ s_right,
    float* __restrict__ query, float* __restrict__ support)
{
    const int tid  = threadIdx.x;
    const int wave = tid >> 6, lane = tid & 63;
    const int quad = lane >> 4, m15 = lane & 15;
    const int pw   = wave >> 1;          // path of this wave (MFMA phase)
    const int wn   = wave & 1;           // n-half
    const int u0   = blockIdx.x * UPB;

    __shared__ __align__(16) unsigned short Sg[4 * 32 * PSTR];  // 4 groups x 32 rows
    __shared__ int   sidxL[UPB][64];
    __shared__ float aP[2][2][32];
    __shared__ float attL[2][32];

    // ---- block init: neighbor indices for all UPB units ----
    {
        int un = tid >> 6, i = tid & 63;
        int uu_ = u0 + un; if (uu_ >= TOTU) uu_ = TOTU - 1;
        const int* conn;
        if (uu_ < BQ)                 conn = q_left  + uu_ * (NBN * 2);
        else if (uu_ < 2 * BQ)        conn = q_right + (uu_ - BQ) * (NBN * 2);
        else if (uu_ < 2 * BQ + FEWN) conn = s_left  + (uu_ - 2 * BQ) * (NBN * 2);
        else                          conn = s_right + (uu_ - 2 * BQ - FEWN) * (NBN * 2);
        sidxL[un][i] = (i < NBN * 2) ? conn[i] : NSYM;
    }

    // ---- per-wave constants: B fragments (128 VGPR), u & bias slices ----
    const unsigned short* Bw = Nbf + (size_t)pw * DD * TWOD;
    const float* Wb = pw ? nvWb : nWb;
    const float* uu = pw ? nvu  : nu;
    bf16x8 Bf[4][8];
    float nb[4], un_[4];
#pragma unroll
    for (int t = 0; t < 4; ++t) {
        int n = wn * 64 + t * 16 + m15;
#pragma unroll
        for (int kt = 0; kt < 8; ++kt)
            Bf[t][kt] = *(const bf16x8*)(Bw + n * TWOD + kt * 32 + quad * 8);
        nb[t] = Wb[n];
        un_[t] = uu[n];
    }
    __syncthreads();

    for (int r = 0; r < UPB; ++r) {
        const int uidx = u0 + r;

        // ---- stage: group = wave; 32 rows x 128 fp32 -> bf16 LDS ----
        {
            const int g = wave;
            const float* table = (g < 2) ? emb : emb_var;
            const int side = g & 1;
            const int colf = (lane & 15) * 8;
            const int rsub = lane >> 4;
#pragma unroll
            for (int i = 0; i < 8; ++i) {
                int row = i * 4 + rsub;
                int sym = sidxL[r][2 * row + side];
                const float* src = table + (size_t)sym * DD + colf;
                float4 x0 = *(const float4*)src;
                float4 x1 = *(const float4*)(src + 4);
                *(bf16x8*)&Sg[(g * 32 + row) * PSTR + colf] = pack8(x0, x1);
            }
        }
        __syncthreads();

        // ---- MFMA: S[32x64 per wave] = cat * W^T ----
        const int pg = pw ? 2 : 0;
        f32x4 acc[2][4] = {};
#pragma unroll
        for (int kt = 0; kt < 8; ++kt) {
            const int g = (kt < 4) ? pg : pg + 1;
            const int coff = (kt & 3) * 32 + quad * 8;
            bf16x8 fa[2];
#pragma unroll
            for (int mt = 0; mt < 2; ++mt)
                fa[mt] = *(const bf16x8*)&Sg[(g * 32 + mt * 16 + m15) * PSTR + coff];
#pragma unroll
            for (int mt = 0; mt < 2; ++mt)
#pragma unroll
                for (int nt = 0; nt < 4; ++nt)
                    acc[mt][nt] = __builtin_amdgcn_mfma_f32_16x16x32_bf16(fa[mt], Bf[nt][kt], acc[mt][nt], 0, 0, 0);
        }

        // ---- epilogue: partial a[m] = sum_n u[n]*tanh(S+b) over this n-half ----
        {
            float part[2][4];
#pragma unroll
            for (int mt = 0; mt < 2; ++mt)
#pragma unroll
                for (int rr = 0; rr < 4; ++rr) {
                    float s = 0.f;
#pragma unroll
                    for (int nt = 0; nt < 4; ++nt)
                        s += un_[nt] * ftanh(acc[mt][nt][rr] + nb[nt]);
                    part[mt][rr] = s;
                }
#pragma unroll
            for (int off = 1; off < 16; off <<= 1)
#pragma unroll
                for (int mt = 0; mt < 2; ++mt)
#pragma unroll
                    for (int rr = 0; rr < 4; ++rr)
                        part[mt][rr] += __shfl_xor(part[mt][rr], off, 64);
            if (m15 == 0) {
#pragma unroll
                for (int mt = 0; mt < 2; ++mt)
#pragma unroll
                    for (int rr = 0; rr < 4; ++rr)
                        aP[pw][wn][mt * 16 + quad * 4 + rr] = part[mt][rr];
            }
        }
        __syncthreads();

        // ---- softmax over 30 neighbors: wave 0 -> p0, wave 2 -> p1 ----
        if ((wave & 1) == 0 && lane < 32) {
            const int p = wave >> 1;
            float sc = (lane < NBN) ? aP[p][0][lane] + aP[p][1][lane] : -1e30f;
            float mx = sc;
#pragma unroll
            for (int off = 1; off < 32; off <<= 1) mx = fmaxf(mx, __shfl_xor(mx, off, 64));
            float e = (lane < NBN) ? __expf(sc - mx) : 0.f;
            float sum = e;
#pragma unroll
            for (int off = 1; off < 32; off <<= 1) sum += __shfl_xor(sum, off, 64);
            attL[p][lane] = e / sum;
        }
        __syncthreads();

        // ---- pool ent_e (group 1, from emb — both paths) + tanh + store ----
        {
            const int p = tid >> 7;          // waves 0,1 -> p0; waves 2,3 -> p1
            const int d = tid & 127;
            float pool = 0.f;
#pragma unroll
            for (int k = 0; k < NBN; ++k)
                pool += attL[p][k] * bf2f(Sg[(32 + k) * PSTR + d]);
            if (uidx < TOTU) {
                float* dst;
                if (uidx < BQ)                 dst = query   + ((size_t)p * BQ + uidx) * TWOD;
                else if (uidx < 2 * BQ)        dst = query   + ((size_t)p * BQ + (uidx - BQ)) * TWOD + DD;
                else if (uidx < 2 * BQ + FEWN) dst = support + ((size_t)p * FEWN + (uidx - 2 * BQ)) * TWOD;
                else                           dst = support + ((size_t)p * FEWN + (uidx - 2 * BQ - FEWN)) * TWOD + DD;
                dst[d] = ftanh(pool);
            }
        }
        __syncthreads();   // protect Sg before next unit's staging
    }
}

// ---------------- K2: support encoder (MLP + residual + layernorm ddof=1) ------
template <int RPB>
__global__ __launch_bounds__(256) void k_supenc(
    const float* __restrict__ xin, float* __restrict__ xout,
    unsigned short* __restrict__ abf,
    const float* __restrict__ p1WT, const float* __restrict__ p1b,
    const float* __restrict__ p2WT, const float* __restrict__ p2b,
    const float* __restrict__ ln_a, const float* __restrict__ ln_b)
{
    const int tid = threadIdx.x;
    const int r0 = blockIdx.x * RPB;
    __shared__ float X[RPB][TWOD];
    __shared__ float H1[RPB][FOURD];
    __shared__ float red[4][RPB][2];
    __shared__ float muv[RPB], sgv[RPB];

    for (int idx = tid; idx < RPB * TWOD; idx += 256) {
        int r = idx >> 8, j = idx & 255;
        X[r][j] = xin[(size_t)(r0 + r) * TWOD + j];
    }
    __syncthreads();

    {
        float acc[RPB][2] = {};
        for (int j = 0; j < TWOD; j += 4) {
            float w0[4], w1[4];
#pragma unroll
            for (int jj = 0; jj < 4; ++jj) {
                w0[jj] = p1WT[(j + jj) * FOURD + tid];
                w1[jj] = p1WT[(j + jj) * FOURD + tid + 256];
            }
#pragma unroll
            for (int r = 0; r < RPB; ++r) {
                float x[4] __attribute__((aligned(16)));
                *(float4*)x = *(const float4*)&X[r][j];
#pragma unroll
                for (int jj = 0; jj < 4; ++jj) {
                    acc[r][0] += x[jj] * w0[jj];
                    acc[r][1] += x[jj] * w1[jj];
                }
            }
        }
        float b0 = p1b[tid], b1 = p1b[tid + 256];
#pragma unroll
        for (int r = 0; r < RPB; ++r) {
            H1[r][tid]       = fmaxf(acc[r][0] + b0, 0.f);
            H1[r][tid + 256] = fmaxf(acc[r][1] + b1, 0.f);
        }
    }
    __syncthreads();

    float z[RPB];
    {
        float acc[RPB] = {};
        for (int j = 0; j < FOURD; j += 4) {
            float w[4];
#pragma unroll
            for (int jj = 0; jj < 4; ++jj) w[jj] = p2WT[(j + jj) * TWOD + tid];
#pragma unroll
            for (int r = 0; r < RPB; ++r) {
                float h[4] __attribute__((aligned(16)));
                *(float4*)h = *(const float4*)&H1[r][j];
#pragma unroll
                for (int jj = 0; jj < 4; ++jj) acc[r] += h[jj] * w[jj];
            }
        }
        float b = p2b[tid];
#pragma unroll
        for (int r = 0; r < RPB; ++r) z[r] = acc[r] + b + X[r][tid];
    }
    {
        float s[RPB], ss[RPB];
#pragma unroll
        for (int r = 0; r < RPB; ++r) { s[r] = z[r]; ss[r] = z[r] * z[r]; }
#pragma unroll
        for (int off = 1; off < 64; off <<= 1)
#pragma unroll
            for (int r = 0; r < RPB; ++r) {
                s[r]  += __shfl_xor(s[r],  off, 64);
                ss[r] += __shfl_xor(ss[r], off, 64);
            }
        const int wv = tid >> 6, lane = tid & 63;
        if (lane == 0) {
#pragma unroll
            for (int r = 0; r < RPB; ++r) { red[wv][r][0] = s[r]; red[wv][r][1] = ss[r]; }
        }
        __syncthreads();
        if (tid < RPB) {
            float st  = red[0][tid][0] + red[1][tid][0] + red[2][tid][0] + red[3][tid][0];
            float sst = red[0][tid][1] + red[1][tid][1] + red[2][tid][1] + red[3][tid][1];
            float mu  = st / (float)TWOD;
            float var = fmaxf((sst - (float)TWOD * mu * mu) / ((float)TWOD - 1.f), 0.f);
            muv[tid] = mu; sgv[tid] = sqrtf(var);
        }
        __syncthreads();
    }
#pragma unroll
    for (int r = 0; r < RPB; ++r) {
        float o = (z[r] - muv[r]) / (sgv[r] + 1e-3f) * ln_a[tid] + ln_b[tid];
        xout[(size_t)(r0 + r) * TWOD + tid] = o;
        if (abf) abf[(size_t)(r0 + r) * KTOT + tid] = f2bf(o);
    }
}

// ---------------- K4a: LSTM gates via bf16 MFMA, fused cell update -------------
__global__ __launch_bounds__(256) void k_lstm_mfma(
    const unsigned short* __restrict__ Abf,
    const unsigned short* __restrict__ Wbf,
    const float* __restrict__ biasR,
    float* __restrict__ cst, float* __restrict__ hbuf)
{
    __shared__ __align__(16) unsigned short As[128 * 32];
    __shared__ __align__(16) unsigned short Bs[128 * 32];
    const int tid  = threadIdx.x;
    const int wave = tid >> 6, lane = tid & 63;
    const int quad = lane >> 4, m15 = lane & 15;
    const int m0 = blockIdx.x * 128;
    const int n0 = blockIdx.y * 128;
    const int wm = wave >> 1, wn = wave & 1;
    const int lrow = lane >> 2, lslot = lane & 3;

    f32x4 acc[4][4] = {};

    for (int kt = 0; kt < KTOT / 32; ++kt) {
        const int k0 = kt * 32;
        __syncthreads();
#pragma unroll
        for (int t = 0; t < 2; ++t) {
            int c = wave * 2 + t;
            int row = c * 16 + lrow;
            int kg = lslot ^ ((row >> 1) & 3);
            gload_lds16(Abf + (size_t)(m0 + row) * KTOT + k0 + kg * 8, As + c * 512);
            gload_lds16(Wbf + (size_t)(n0 + row) * KTOT + k0 + kg * 8, Bs + c * 512);
        }
        __syncthreads();

        bf16x8 fa[4], fb[4];
#pragma unroll
        for (int mi = 0; mi < 4; ++mi) {
            int ra = wm * 64 + mi * 16 + m15;
            int sa = quad ^ ((ra >> 1) & 3);
            fa[mi] = *(const bf16x8*)(As + ra * 32 + sa * 8);
            int rb = wn * 64 + mi * 16 + m15;
            int sb = quad ^ ((rb >> 1) & 3);
            fb[mi] = *(const bf16x8*)(Bs + rb * 32 + sb * 8);
        }
#pragma unroll
        for (int mi = 0; mi < 4; ++mi)
#pragma unroll
            for (int ni = 0; ni < 4; ++ni)
                acc[mi][ni] = __builtin_amdgcn_mfma_f32_16x16x32_bf16(fa[mi], fb[ni], acc[mi][ni], 0, 0, 0);
    }

    const int u = ((n0 + wn * 64) >> 2) + m15;
    float bg[4];
#pragma unroll
    for (int g = 0; g < 4; ++g) bg[g] = biasR[n0 + wn * 64 + g * 16 + m15];
#pragma unroll
    for (int mi = 0; mi < 4; ++mi) {
#pragma unroll
        for (int r = 0; r < 4; ++r) {
            int gm = m0 + wm * 64 + mi * 16 + quad * 4 + r;
            size_t cidx = (size_t)gm * ULIVE + u;
            float pi = acc[mi][0][r] + bg[0];
            float pf = acc[mi][1][r] + bg[1];
            float pg = acc[mi][2][r] + bg[2];
            float po = acc[mi][3][r] + bg[3];
            float cn = sigmoidf_(pf) * cst[cidx] + sigmoidf_(pi) * tanhf(pg);
            cst[cidx]  = cn;
            hbuf[cidx] = sigmoidf_(po) * tanhf(cn);
        }
    }
}

// ---------------- K4b: h, attention over support, write bf16 h|r ---------------
__global__ __launch_bounds__(256) void k_lstm_attn(
    const float* __restrict__ qg, const float* __restrict__ hbuf,
    const float* __restrict__ sg, unsigned short* __restrict__ Abf,
    float* __restrict__ hfin)
{
    const int tid = threadIdx.x;
    const int p   = blockIdx.y;
    const int wv = tid >> 6, lane = tid & 63;
    __shared__ float sgl[FEWN][TWOD];
    for (int idx = tid; idx < FEWN * TWOD; idx += 256)
        sgl[idx >> 8][idx & 255] = sg[p * FEWN * TWOD + idx];
    __syncthreads();
    const int j0 = lane * 4;
    for (int rr = 0; rr < 8; ++rr) {
        int row = blockIdx.x * 32 + wv * 8 + rr;
        size_t g = (size_t)p * BQ + row;
        float4 q4 = *(const float4*)(qg + g * TWOD + j0);
        float4 t4 = *(const float4*)(hbuf + g * ULIVE + j0);
        float h[4] __attribute__((aligned(16))) = {q4.x + t4.x, q4.y + t4.y, q4.z + t4.z, q4.w + t4.w};
        float sv[FEWN][4] __attribute__((aligned(16)));
        float pa[FEWN];
#pragma unroll
        for (int f = 0; f < FEWN; ++f) {
            *(float4*)sv[f] = *(const float4*)&sgl[f][j0];
            pa[f] = h[0] * sv[f][0] + h[1] * sv[f][1] + h[2] * sv[f][2] + h[3] * sv[f][3];
        }
#pragma unroll
        for (int off = 1; off < 64; off <<= 1)
#pragma unroll
            for (int f = 0; f < FEWN; ++f) pa[f] += __shfl_xor(pa[f], off, 64);
        float mx = pa[0];
#pragma unroll
        for (int f = 1; f < FEWN; ++f) mx = fmaxf(mx, pa[f]);
        float sum = 0.f, e[FEWN];
#pragma unroll
        for (int f = 0; f < FEWN; ++f) { e[f] = expf(pa[f] - mx); sum += e[f]; }
        float inv = 1.f / sum;
        float r4[4] __attribute__((aligned(16))) = {0.f, 0.f, 0.f, 0.f};
#pragma unroll
        for (int f = 0; f < FEWN; ++f) {
            float a = e[f] * inv;
#pragma unroll
            for (int q = 0; q < 4; ++q) r4[q] += a * sv[f][q];
        }
        unsigned short tb[4] __attribute__((aligned(8)));
#pragma unroll
        for (int q = 0; q < 4; ++q) tb[q] = f2bf(h[q]);
        *(uint2*)(Abf + g * KTOT + TWOD + j0) = *(uint2*)tb;
#pragma unroll
        for (int q = 0; q < 4; ++q) tb[q] = f2bf(r4[q]);
        *(uint2*)(Abf + g * KTOT + FOURD + j0) = *(uint2*)tb;
        *(float4*)(hfin + g * TWOD + j0) = *(float4*)h;
    }
}

// ---------------- K5: final scores ---------------------------------------------
__global__ __launch_bounds__(256) void k_score(
    const float* __restrict__ hfin, const float* __restrict__ sg, float* __restrict__ out)
{
    const int tid = threadIdx.x;
    const int p   = blockIdx.y;
    __shared__ float sm[TWOD];
    if (tid < TWOD) {
        const float* s = sg + p * FEWN * TWOD + tid;
        sm[tid] = (s[0] + s[TWOD] + s[2 * TWOD] + s[3 * TWOD] + s[4 * TWOD]) / 5.0f;
    }
    __syncthreads();
    const int wv = tid >> 6, lane = tid & 63;
    const int j0 = lane * 4;
    for (int rr = 0; rr < 8; ++rr) {
        int row = blockIdx.x * 32 + wv * 8 + rr;
        const float* h = hfin + ((size_t)p * BQ + row) * TWOD + j0;
        float4 h4 = *(const float4*)h;
        float4 s4 = *(const float4*)&sm[j0];
        float pv = h4.x * s4.x + h4.y * s4.y + h4.z * s4.z + h4.w * s4.w;
#pragma unroll
        for (int off = 1; off < 64; off <<= 1) pv += __shfl_xor(pv, off, 64);
        if (lane == 0) out[p * BQ + row] = pv;
    }
}

extern "C" void kernel_launch(void* const* d_in, const int* in_sizes, int n_in,
                              void* d_out, int out_size, void* d_ws, size_t ws_size,
                              hipStream_t stream)
{
    const float* emb     = (const float*)d_in[0];
    const float* emb_var = (const float*)d_in[1];
    const float* nW      = (const float*)d_in[2];
    const float* nWb     = (const float*)d_in[3];
    const float* nu      = (const float*)d_in[4];
    const float* nub     = (const float*)d_in[5];
    const float* nvW     = (const float*)d_in[6];
    const float* nvWb    = (const float*)d_in[7];
    const float* nvu     = (const float*)d_in[8];
    const float* nvub    = (const float*)d_in[9];
    const float* p1W     = (const float*)d_in[10];
    const float* p1b     = (const float*)d_in[11];
    const float* p2W     = (const float*)d_in[12];
    const float* p2b     = (const float*)d_in[13];
    const float* ln_a    = (const float*)d_in[14];
    const float* ln_b    = (const float*)d_in[15];
    const float* Wih     = (const float*)d_in[16];
    const float* Whh     = (const float*)d_in[17];
    const float* bih     = (const float*)d_in[18];
    const float* bhh     = (const float*)d_in[19];
    const int* q_left    = (const int*)d_in[20];
    const int* q_right   = (const int*)d_in[21];
    const int* s_left    = (const int*)d_in[22];
    const int* s_right   = (const int*)d_in[23];

    float* ws = (float*)d_ws;
    size_t o = 0;
    float* p1WT     = ws + o; o += FOURD * TWOD;
    float* p2WT     = ws + o; o += FOURD * TWOD;
    float* biasR    = ws + o; o += NGATE;
    float* query    = ws + o; o += (size_t)2 * BQ * TWOD;    // reused as hfin
    float* supportB = ws + o; o += 2 * FEWN * TWOD;
    float* qg       = ws + o; o += (size_t)2 * BQ * TWOD;
    float* sg       = ws + o; o += 2 * FEWN * TWOD;
    float* cst      = ws + o; o += (size_t)2 * BQ * ULIVE;
    float* hbuf     = ws + o; o += (size_t)2 * BQ * ULIVE;
    unsigned short* Wbf = (unsigned short*)(ws + o); o += (size_t)NGATE * KTOT / 2;
    unsigned short* Abf = (unsigned short*)(ws + o); o += (size_t)2 * BQ * KTOT / 2;
    unsigned short* Nbf = (unsigned short*)(ws + o); o += (size_t)2 * DD * TWOD / 2;
    float* hfin     = query;

    hipMemsetAsync(cst, 0, (size_t)2 * BQ * ULIVE * sizeof(float), stream);
    hipMemsetAsync(Abf, 0, (size_t)2 * BQ * KTOT * sizeof(unsigned short), stream);

    k_prep<<<dim3(1024), dim3(256), 0, stream>>>(Wih, Whh, bih, bhh, p1W, p2W, nW, nvW,
                                                 Wbf, biasR, p1WT, p2WT, Nbf);
    k_neighbor_v4<<<dim3((TOTU + UPB - 1) / UPB), dim3(256), 0, stream>>>(
        emb, emb_var, Nbf, nWb, nu, nvWb, nvu,
        q_left, q_right, s_left, s_right, query, supportB);
    k_supenc<8><<<dim3(2 * BQ / 8), dim3(256), 0, stream>>>(query, qg, Abf, p1WT, p1b, p2WT, p2b, ln_a, ln_b);
    k_supenc<1><<<dim3(2 * FEWN), dim3(256), 0, stream>>>(supportB, sg, (unsigned short*)nullptr,
                                                          p1WT, p1b, p2WT, p2b, ln_a, ln_b);
    for (int s = 0; s < 4; ++s) {
        k_lstm_mfma<<<dim3(2 * BQ / 128, NGATE / 128), dim3(256), 0, stream>>>(Abf, Wbf, biasR, cst, hbuf);
        k_lstm_attn<<<dim3(BQ / 32, 2), dim3(256), 0, stream>>>(qg, hbuf, sg, Abf, hfin);
    }
    k_score<<<dim3(BQ / 32, 2), dim3(256), 0, stream>>>(hfin, sg, (float*)d_out);
}